// Round 13
// baseline (1187.334 us; speedup 1.0000x reference)
//
#include <hip/hip_runtime.h>
#include <hip/hip_bf16.h>

#define NLAYERS 6
#define Bc 2
#define Tc 13294
#define Ec 256
#define NHc 8
#define FFNc 1024

#define EPI_BIAS 0
#define EPI_MASK 1
#define EPI_RES  2
#define EPI_RELU 3
#define EPI_VALOA 4

typedef __attribute__((ext_vector_type(8))) short bf16x8;
typedef __attribute__((ext_vector_type(4))) float f32x4;

typedef __attribute__((address_space(3))) unsigned int u32_lds;
typedef __attribute__((address_space(1))) unsigned int u32_glb;

__device__ __forceinline__ void gld16(const void* g, void* l) {
    __builtin_amdgcn_global_load_lds((const u32_glb*)g, (u32_lds*)l, 16, 0, 0);
}

__device__ __forceinline__ short f2bf(float f) {
    union { float f; unsigned u; } v; v.f = f;
    unsigned r = v.u + 0x7FFFu + ((v.u >> 16) & 1u);
    return (short)(r >> 16);
}
__device__ __forceinline__ float bf2f(short s) {
    union { unsigned u; float f; } v; v.u = ((unsigned)(unsigned short)s) << 16;
    return v.f;
}
__device__ __forceinline__ float bf_lo(unsigned u) {
    union { unsigned u; float f; } v; v.u = u << 16; return v.f;
}

// ---------------- LayerNorm fp32-in (+ q = x + pos), bf16 outputs; layer 0 only ----------------
__global__ __launch_bounds__(256) void ln_kernel(
    const float* __restrict__ src, const float* __restrict__ pos,
    const float* __restrict__ g, const float* __restrict__ b,
    short* __restrict__ x, short* __restrict__ q, int rows)
{
    int wave = threadIdx.x >> 6;
    int lane = threadIdx.x & 63;
    int row = blockIdx.x * 4 + wave;
    if (row >= rows) return;
    const float* p = src + (size_t)row * Ec;
    float4 v = *(const float4*)(p + lane * 4);
    float s  = v.x + v.y + v.z + v.w;
    float sq = v.x*v.x + v.y*v.y + v.z*v.z + v.w*v.w;
    #pragma unroll
    for (int o = 32; o; o >>= 1) { s += __shfl_xor(s, o); sq += __shfl_xor(sq, o); }
    float mean = s * (1.f / Ec);
    float var  = sq * (1.f / Ec) - mean * mean;
    float inv  = rsqrtf(var + 1e-5f);
    float4 gg = *(const float4*)(g + lane * 4);
    float4 bb = *(const float4*)(b + lane * 4);
    float xo0 = (v.x - mean) * inv * gg.x + bb.x;
    float xo1 = (v.y - mean) * inv * gg.y + bb.y;
    float xo2 = (v.z - mean) * inv * gg.z + bb.z;
    float xo3 = (v.w - mean) * inv * gg.w + bb.w;
    short4 xs; xs.x = f2bf(xo0); xs.y = f2bf(xo1); xs.z = f2bf(xo2); xs.w = f2bf(xo3);
    *(short4*)(x + (size_t)row * Ec + lane * 4) = xs;
    float4 pp = *(const float4*)(pos + (size_t)row * Ec + lane * 4);
    short4 qs;
    qs.x = f2bf(xo0 + pp.x); qs.y = f2bf(xo1 + pp.y);
    qs.z = f2bf(xo2 + pp.z); qs.w = f2bf(xo3 + pp.w);
    *(short4*)(q + (size_t)row * Ec + lane * 4) = qs;
}

// ---------------- LayerNorm bf16-in, bf16 out (+ optional q = x + pos_fp32) ----------------
__global__ __launch_bounds__(256) void ln_bf_kernel(
    const short* __restrict__ src, const float* __restrict__ pos,
    const float* __restrict__ g, const float* __restrict__ b,
    short* __restrict__ x, short* __restrict__ q, int rows)
{
    int wave = threadIdx.x >> 6;
    int lane = threadIdx.x & 63;
    int row = blockIdx.x * 4 + wave;
    if (row >= rows) return;
    short4 v4 = *(const short4*)(src + (size_t)row * Ec + lane * 4);
    float v0 = bf2f(v4.x), v1 = bf2f(v4.y), v2 = bf2f(v4.z), v3 = bf2f(v4.w);
    float s  = v0 + v1 + v2 + v3;
    float sq = v0*v0 + v1*v1 + v2*v2 + v3*v3;
    #pragma unroll
    for (int o = 32; o; o >>= 1) { s += __shfl_xor(s, o); sq += __shfl_xor(sq, o); }
    float mean = s * (1.f / Ec);
    float var  = sq * (1.f / Ec) - mean * mean;
    float inv  = rsqrtf(var + 1e-5f);
    float4 gg = *(const float4*)(g + lane * 4);
    float4 bb = *(const float4*)(b + lane * 4);
    float xo0 = (v0 - mean) * inv * gg.x + bb.x;
    float xo1 = (v1 - mean) * inv * gg.y + bb.y;
    float xo2 = (v2 - mean) * inv * gg.z + bb.z;
    float xo3 = (v3 - mean) * inv * gg.w + bb.w;
    short4 xs; xs.x = f2bf(xo0); xs.y = f2bf(xo1); xs.z = f2bf(xo2); xs.w = f2bf(xo3);
    *(short4*)(x + (size_t)row * Ec + lane * 4) = xs;
    if (q) {
        float4 pp = *(const float4*)(pos + (size_t)row * Ec + lane * 4);
        short4 qs;
        qs.x = f2bf(xo0 + pp.x); qs.y = f2bf(xo1 + pp.y);
        qs.z = f2bf(xo2 + pp.z); qs.w = f2bf(xo3 + pp.w);
        *(short4*)(q + (size_t)row * Ec + lane * 4) = qs;
    }
}

// ---------------- merged weight transpose+convert: all 6 weights in one dispatch ----------------
__global__ __launch_bounds__(256) void transpose_all(
    const float* __restrict__ Wv,   const float* __restrict__ Woff,
    const float* __restrict__ Wattn,const float* __restrict__ Wout,
    const float* __restrict__ W1,   const float* __restrict__ W2,
    short* __restrict__ wcT, short* __restrict__ woutT,
    short* __restrict__ w1T, short* __restrict__ w2T)
{
    __shared__ float tile[32][33];
    const int l = blockIdx.z;
    const int t = blockIdx.x;
    const float* W; short* Wt; int K, N, lstr, rowOff, n0, k0;
    if (t < 64)       { W = Wv;    Wt = wcT;   K = 256;  N = 256;  lstr = 163840; rowOff = 0;
                        int u = t;        n0 = (u & 7) * 32;  k0 = (u >> 3) * 32; }
    else if (t < 128) { W = Woff;  Wt = wcT;   K = 256;  N = 256;  lstr = 163840; rowOff = 256;
                        int u = t - 64;   n0 = (u & 7) * 32;  k0 = (u >> 3) * 32; }
    else if (t < 160) { W = Wattn; Wt = wcT;   K = 256;  N = 128;  lstr = 163840; rowOff = 512;
                        int u = t - 128;  n0 = (u & 3) * 32;  k0 = (u >> 2) * 32; }
    else if (t < 224) { W = Wout;  Wt = woutT; K = 256;  N = 256;  lstr = 65536;  rowOff = 0;
                        int u = t - 160;  n0 = (u & 7) * 32;  k0 = (u >> 3) * 32; }
    else if (t < 480) { W = W1;    Wt = w1T;   K = 256;  N = 1024; lstr = 262144; rowOff = 0;
                        int u = t - 224;  n0 = (u & 31) * 32; k0 = (u >> 5) * 32; }
    else              { W = W2;    Wt = w2T;   K = 1024; N = 256;  lstr = 262144; rowOff = 0;
                        int u = t - 480;  n0 = (u & 7) * 32;  k0 = (u >> 3) * 32; }
    const float* Wl = W + (size_t)l * K * N;
    short* Wtl = Wt + (size_t)l * lstr;
    int tx = threadIdx.x & 31, ty = threadIdx.x >> 5;
    #pragma unroll
    for (int i = 0; i < 32; i += 8)
        tile[ty + i][tx] = Wl[(size_t)(k0 + ty + i) * N + n0 + tx];
    __syncthreads();
    #pragma unroll
    for (int i = 0; i < 32; i += 8)
        Wtl[(size_t)(rowOff + n0 + ty + i) * K + k0 + tx] = f2bf(tile[tx][ty + i]);
}

// ---------------- bf16 MFMA GEMM: 128x64 tile, BK=32, 3-deep LDS pipeline ----------------
// Counted vmcnt (never 0 in steady state): per iteration
//   s_barrier (all waves done reading the buffer about to be overwritten)
//   STAGE(buf[i+2]) ; s_waitcnt vmcnt(6)  (oldest stage's 3 loads done; 6 stay in flight)
//   s_barrier (collective: buffer i landed for ALL waves) ; compute(buf[i])
// EPI_VALOA: A2 for col>=256 blocks; out col<256 -> Cout2 (valb, mask), col>=256 -> Cout
// (oab stride 384); biases bias/bias2/bias3 per segment.
template<int EPI, int OBF, int RESBF>
__global__ __launch_bounds__(256) void gemm_mfma(
    const short* __restrict__ A, const short* __restrict__ A2,
    const short* __restrict__ Bt,
    const float* __restrict__ bias, const float* __restrict__ bias2,
    const float* __restrict__ bias3,
    const float* __restrict__ resf, const short* __restrict__ resb,
    const unsigned char* __restrict__ mask,
    void* __restrict__ Cout, void* __restrict__ Cout2, int M, int N, int K)
{
    __shared__ short As[3][128 * 32];
    __shared__ short Bs[3][64 * 32];
    const int tid = threadIdx.x;
    const int lane = tid & 63;
    const int wv = tid >> 6;
    const int row0 = blockIdx.x * 128;
    const int col0 = blockIdx.y * 64;
    const int mbase = (wv >> 1) * 64;   // wave tile: 64 rows x 32 cols
    const int nbase = (wv & 1) * 32;
    const int lr = lane & 15;
    const int kg = lane >> 4;

    const short* Ause = (EPI == EPI_VALOA && blockIdx.y >= 4) ? A2 : A;

    f32x4 zf = {0.f, 0.f, 0.f, 0.f};
    f32x4 acc[4][2];
    #pragma unroll
    for (int i = 0; i < 4; ++i)
        #pragma unroll
        for (int j = 0; j < 2; ++j) acc[i][j] = zf;

    const int scol = (lane & 3) * 8;
    const int srowA = wv * 32 + (lane >> 2);
    const short* Ap = Ause + (size_t)(row0 + srowA) * K + scol;
    const int lA0 = srowA * 32 + scol;
    const int lA1 = lA0 + 16 * 32;
    const int srowB = wv * 16 + (lane >> 2);
    const short* Bp = Bt + (size_t)(col0 + srowB) * K + scol;
    const int lB = srowB * 32 + scol;

    #define STAGE(buf, k0) do { \
        gld16(Ap + (k0),                &As[buf][lA0]); \
        gld16(Ap + (size_t)16*K + (k0), &As[buf][lA1]); \
        gld16(Bp + (k0),                &Bs[buf][lB]); \
    } while (0)

    const int nIter = K >> 5;
    STAGE(0, 0);
    if (nIter > 1) STAGE(1, 32);

    int cb = 0;          // compute buffer
    int sb = 2;          // stage buffer
    for (int i = 0; i < nIter; ++i) {
        // barrier #1: all waves finished reading buf[sb] (last computed 2 iters ago)
        __builtin_amdgcn_s_barrier();
        if (i + 2 < nIter) {
            STAGE(sb, (i + 2) * 32);
            asm volatile("s_waitcnt vmcnt(6)" ::: "memory");
        } else if (i + 1 < nIter) {
            asm volatile("s_waitcnt vmcnt(3)" ::: "memory");
        } else {
            asm volatile("s_waitcnt vmcnt(0)" ::: "memory");
        }
        // barrier #2: every wave has waited for its own buf[cb] loads -> collective ready
        __builtin_amdgcn_s_barrier();
        __builtin_amdgcn_sched_barrier(0);
        bf16x8 af[4], bfr[2];
        #pragma unroll
        for (int ii = 0; ii < 4; ++ii)
            af[ii]  = *(const bf16x8*)&As[cb][(mbase + ii * 16 + lr) * 32 + kg * 8];
        #pragma unroll
        for (int jj = 0; jj < 2; ++jj)
            bfr[jj] = *(const bf16x8*)&Bs[cb][(nbase + jj * 16 + lr) * 32 + kg * 8];
        #pragma unroll
        for (int mi = 0; mi < 4; ++mi)
            #pragma unroll
            for (int ni = 0; ni < 2; ++ni)
                acc[mi][ni] = __builtin_amdgcn_mfma_f32_16x16x32_bf16(
                    af[mi], bfr[ni], acc[mi][ni], 0, 0, 0);
        cb = (cb == 2) ? 0 : cb + 1;
        sb = (sb == 2) ? 0 : sb + 1;
    }
    #undef STAGE

    float* Cf = (float*)Cout;
    short* Cb2 = (short*)Cout;
    short* Vb = (short*)Cout2;
    #pragma unroll
    for (int ni = 0; ni < 2; ++ni) {
        int col = col0 + nbase + ni * 16 + lr;
        float bz;
        if (EPI == EPI_VALOA)
            bz = (col < 256) ? bias[col] : ((col < 512) ? bias2[col - 256] : bias3[col - 512]);
        else
            bz = (bias2 && col >= 256) ? bias2[col - 256] : bias[col];
        #pragma unroll
        for (int mi = 0; mi < 4; ++mi) {
            int rb = row0 + mbase + mi * 16 + kg * 4;
            #pragma unroll
            for (int j = 0; j < 4; ++j) {
                int grow = rb + j;
                if (grow >= M) continue;
                float v = acc[mi][ni][j] + bz;
                if (EPI == EPI_VALOA) {
                    if (col < 256) {
                        if (mask[grow]) v = 0.f;
                        Vb[(size_t)grow * 256 + col] = f2bf(v);
                    } else {
                        Cb2[(size_t)grow * 384 + (col - 256)] = f2bf(v);
                    }
                    continue;
                }
                if (EPI == EPI_MASK) { if (mask[grow]) v = 0.f; }
                if (EPI == EPI_RES) {
                    v += RESBF ? bf2f(resb[(size_t)grow * N + col])
                               : resf[(size_t)grow * N + col];
                }
                if (EPI == EPI_RELU) v = v > 0.f ? v : 0.f;
                if (OBF) Cb2[(size_t)grow * N + col] = f2bf(v);
                else     Cf[(size_t)grow * N + col] = v;
            }
        }
    }
}

// ---------------- MSDA with fused softmax; value + oa bf16 ----------------
// block = one bq (all 8 heads); phase-1 compacted onto threads 0..127 (2 full waves);
// phase-2: 32-lane group per head; lane owns 2 dims (dword, 16 lanes/64B row).
// pts layout conflict-free ({0,4,8,12} bank starts).
// phase-1 algebra: xf = (refx + ox/w)*w - 0.5 == refx*w + ox - 0.5  (kills 2 divides).
__global__ __launch_bounds__(256) void msda_kernel(
    const short* __restrict__ value, const short* __restrict__ oa,
    const float* __restrict__ vr, short* __restrict__ out)
{
    __shared__ int pts[8 * 136];
    const int t = threadIdx.x;
    const int bq = blockIdx.x;
    const int b = (bq >= Tc) ? 1 : 0;
    const int qq = bq - b * Tc;

    if (t < 128) {
        const int g = t >> 4;        // group == head
        const int p = t & 15;
        const int lvl = p >> 2;
        const int St[4] = {0, 10000, 12500, 13125};
        int qi, Wq, qlvl;
        if (qq < 10000)      { qlvl = 0; qi = qq;         Wq = 100; }
        else if (qq < 12500) { qlvl = 1; qi = qq - 10000; Wq = 50; }
        else if (qq < 13125) { qlvl = 2; qi = qq - 12500; Wq = 25; }
        else                 { qlvl = 3; qi = qq - 13125; Wq = 13; }
        float base_x = (0.5f + (float)(qi % Wq)) / (vr[(b*4+qlvl)*2+0] * (float)Wq);
        float base_y = (0.5f + (float)(qi / Wq)) / (vr[(b*4+qlvl)*2+1] * (float)Wq);

        // softmax over 16 logits (one per lane; 16-lane group is wave-aligned)
        float logit = bf2f(oa[(size_t)bq * 384 + 256 + g * 16 + p]);
        float mx = logit;
        #pragma unroll
        for (int o = 8; o; o >>= 1) mx = fmaxf(mx, __shfl_xor(mx, o));
        float e = __expf(logit - mx);
        float sum = e;
        #pragma unroll
        for (int o = 8; o; o >>= 1) sum += __shfl_xor(sum, o);
        float aw = e / sum;

        const int w = (lvl == 0) ? 100 : ((lvl == 1) ? 50 : ((lvl == 2) ? 25 : 13));
        const int hh = w;
        const float wf = (float)w;
        const float refxw = base_x * vr[(b*4+lvl)*2+0] * wf;
        const float refyw = base_y * vr[(b*4+lvl)*2+1] * wf;
        const float ox = bf2f(oa[(size_t)bq * 384 + g * 32 + p * 2 + 0]);
        const float oy = bf2f(oa[(size_t)bq * 384 + g * 32 + p * 2 + 1]);
        float xf = refxw + ox - 0.5f;
        float yf = refyw + oy - 0.5f;
        float x0f = floorf(xf), y0f = floorf(yf);
        int x0 = (int)x0f, y0 = (int)y0f;
        float wx = xf - x0f, wy = yf - y0f;
        float w00 = (1.f - wx) * (1.f - wy) * aw;
        float w10 = wx * (1.f - wy) * aw;
        float w01 = (1.f - wx) * wy * aw;
        float w11 = wx * wy * aw;
        bool vx0 = (x0 >= 0) && (x0 < w);
        bool vx1 = (x0 + 1 >= 0) && (x0 + 1 < w);
        bool vy0 = (y0 >= 0) && (y0 < hh);
        bool vy1 = (y0 + 1 >= 0) && (y0 + 1 < hh);
        if (!(vx0 && vy0)) w00 = 0.f;
        if (!(vx1 && vy0)) w10 = 0.f;
        if (!(vx0 && vy1)) w01 = 0.f;
        if (!(vx1 && vy1)) w11 = 0.f;
        int cx0 = min(max(x0, 0), w - 1), cx1 = min(max(x0 + 1, 0), w - 1);
        int cy0 = min(max(y0, 0), hh - 1), cy1 = min(max(y0 + 1, 0), hh - 1);
        int rowbase = b * Tc + St[lvl];
        int slot = g * 136 + p * 8 + ((p >> 3) & 1) * 4;
        int4 wq4; wq4.x = __float_as_int(w00); wq4.y = __float_as_int(w10);
        wq4.z = __float_as_int(w01); wq4.w = __float_as_int(w11);
        int4 aq4;
        aq4.x = (rowbase + cy0 * w + cx0) * 512 + g * 64;
        aq4.y = (rowbase + cy0 * w + cx1) * 512 + g * 64;
        aq4.z = (rowbase + cy1 * w + cx0) * 512 + g * 64;
        aq4.w = (rowbase + cy1 * w + cx1) * 512 + g * 64;
        *(int4*)&pts[slot] = wq4;
        *(int4*)&pts[slot + 4] = aq4;
    }
    __syncthreads();

    const int group = t >> 5;               // head
    const int l32 = t & 31;
    const int d4 = (l32 & 15) * 4;
    const int ph = (l32 >> 4) * 8;
    const int xw = (l32 >> 4) * 4;
    const char* vbase = (const char*)value;
    float accL = 0.f, accH = 0.f;
    #pragma unroll
    for (int j = 0; j < 8; ++j) {
        int p = ph + j;
        int slot = group * 136 + p * 8 + xw;
        int4 wq = *(const int4*)&pts[slot];
        int4 aq = *(const int4*)&pts[slot + 4];
        unsigned u0 = *(const unsigned*)(vbase + (unsigned)(aq.x + d4));
        unsigned u1 = *(const unsigned*)(vbase + (unsigned)(aq.y + d4));
        unsigned u2 = *(const unsigned*)(vbase + (unsigned)(aq.z + d4));
        unsigned u3 = *(const unsigned*)(vbase + (unsigned)(aq.w + d4));
        float w00 = __int_as_float(wq.x), w10 = __int_as_float(wq.y);
        float w01 = __int_as_float(wq.z), w11 = __int_as_float(wq.w);
        // hi half: raw reinterpret (garbage low mantissa bits << bf16 rounding error)
        accL = fmaf(w00, bf_lo(u0), accL); accH = fmaf(w00, __int_as_float((int)u0), accH);
        accL = fmaf(w10, bf_lo(u1), accL); accH = fmaf(w10, __int_as_float((int)u1), accH);
        accL = fmaf(w01, bf_lo(u2), accL); accH = fmaf(w01, __int_as_float((int)u2), accH);
        accL = fmaf(w11, bf_lo(u3), accL); accH = fmaf(w11, __int_as_float((int)u3), accH);
    }
    accL += __shfl_xor(accL, 16);
    accH += __shfl_xor(accH, 16);
    if (l32 < 16) {
        unsigned pk = ((unsigned)(unsigned short)f2bf(accL)) |
                      (((unsigned)(unsigned short)f2bf(accH)) << 16);
        *(unsigned*)((char*)out + (size_t)bq * 512 + group * 64 + d4) = pk;
    }
}

extern "C" void kernel_launch(void* const* d_in, const int* in_sizes, int n_in,
                              void* d_out, int out_size, void* d_ws, size_t ws_size,
                              hipStream_t stream) {
    const float* src  = (const float*)d_in[0];
    const float* pos  = (const float*)d_in[1];
    const float* vr   = (const float*)d_in[2];
    const unsigned char* mask = (const unsigned char*)d_in[5];
    const float* Wv    = (const float*)d_in[6];
    const float* bv    = (const float*)d_in[7];
    const float* Woff  = (const float*)d_in[8];
    const float* boff  = (const float*)d_in[9];
    const float* Wattn = (const float*)d_in[10];
    const float* battn = (const float*)d_in[11];
    const float* Wout  = (const float*)d_in[12];
    const float* bout  = (const float*)d_in[13];
    const float* n1g   = (const float*)d_in[14];
    const float* n1b   = (const float*)d_in[15];
    const float* n2g   = (const float*)d_in[16];
    const float* n2b   = (const float*)d_in[17];
    const float* W1    = (const float*)d_in[18];
    const float* b1    = (const float*)d_in[19];
    const float* W2    = (const float*)d_in[20];
    const float* b2    = (const float*)d_in[21];
    float* out = (float*)d_out;

    const size_t R = (size_t)Bc * Tc;   // 26588

    // shorts/row: xb 256 | qb 256 | valb 256 | msdab 256 | oab 384 | srcb 256
    short* xb    = (short*)d_ws;
    short* qb    = xb + R * 256;
    short* valb  = qb + R * 256;
    short* msdab = valb + R * 256;
    short* oab   = msdab + R * 256;           // R*384
    short* srcb  = oab + R * 384;             // R*256 bf16 residual stream
    short* ln2b  = xb;                        // alias: xb dead by LN2 time
    short* hb    = qb;                        // alias: qb..oab >= R*1024, dead by ffn1
    short* wcT   = srcb + R * 256;            // 6*163840 ([640][256]: Wv|Woff|Wattn)
    short* woutT = wcT + 6 * 163840;          // 6*65536
    short* w1T   = woutT + 6 * 65536;         // 6*262144 ([1024][256])
    short* w2T   = w1T + 6 * 262144;          // 6*262144 ([256][1024])

    // one-time setup: all weight transposes in a single dispatch
    transpose_all<<<dim3(736, 1, 6), 256, 0, stream>>>(
        Wv, Woff, Wattn, Wout, W1, W2, wcT, woutT, w1T, w2T);

    const int M = (int)R;
    const int lnBlocks = (int)((R + 3) / 4);
    const int MT = (int)((R + 127) / 128);  // 208

    // layer 0 LN1 (fp32 src input)
    ln_kernel<<<lnBlocks, 256, 0, stream>>>(src, pos, n1g, n1b, xb, qb, M);

    for (int l = 0; l < NLAYERS; ++l) {
        // merged: [value | off | logits]; A = xb for cols<256, qb otherwise
        gemm_mfma<EPI_VALOA, 1, 0><<<dim3(MT, 10), 256, 0, stream>>>(
            xb, qb, wcT + (size_t)l * 163840, bv + l * Ec, boff + l * 256, battn + l * 128,
            nullptr, nullptr, mask, oab, valb, M, 640, 256);
        // MSDA (softmax fused) -> bf16
        msda_kernel<<<(int)R, 256, 0, stream>>>(valb, oab, vr, msdab);
        // src2 = cur + msda @ Wout + bout -> bf16 srcb
        if (l == 0)
            gemm_mfma<EPI_RES, 1, 0><<<dim3(MT, 4), 256, 0, stream>>>(
                msdab, nullptr, woutT + (size_t)l * 65536, bout + l * Ec, nullptr, nullptr,
                src, nullptr, nullptr, srcb, nullptr, M, 256, 256);
        else
            gemm_mfma<EPI_RES, 1, 1><<<dim3(MT, 4), 256, 0, stream>>>(
                msdab, nullptr, woutT + (size_t)l * 65536, bout + l * Ec, nullptr, nullptr,
                nullptr, srcb, nullptr, srcb, nullptr, M, 256, 256);
        // LN2 (bf16 in/out) -> ln2b
        ln_bf_kernel<<<lnBlocks, 256, 0, stream>>>(srcb, nullptr, n2g + l * Ec, n2b + l * Ec,
                                                   ln2b, nullptr, M);
        // h = relu(ln2 @ W1 + b1) -> bf16
        gemm_mfma<EPI_RELU, 1, 0><<<dim3(MT, 16), 256, 0, stream>>>(
            ln2b, nullptr, w1T + (size_t)l * 262144, b1 + l * FFNc, nullptr, nullptr,
            nullptr, nullptr, nullptr, hb, nullptr, M, 1024, 256);
        // src = src2 + h @ W2 + b2 ; last layer -> fp32 out, else bf16 srcb
        if (l < NLAYERS - 1) {
            gemm_mfma<EPI_RES, 1, 1><<<dim3(MT, 4), 256, 0, stream>>>(
                hb, nullptr, w2T + (size_t)l * 262144, b2 + l * Ec, nullptr, nullptr,
                nullptr, srcb, nullptr, srcb, nullptr, M, 256, 1024);
            // next-layer LN1 (+ q = x + pos, pos read fp32)
            ln_bf_kernel<<<lnBlocks, 256, 0, stream>>>(srcb, pos, n1g + (l + 1) * Ec,
                                                       n1b + (l + 1) * Ec, xb, qb, M);
        } else {
            gemm_mfma<EPI_RES, 0, 1><<<dim3(MT, 4), 256, 0, stream>>>(
                hb, nullptr, w2T + (size_t)l * 262144, b2 + l * Ec, nullptr, nullptr,
                nullptr, srcb, nullptr, out, nullptr, M, 256, 1024);
        }
    }
}

// Round 14
// 1131.863 us; speedup vs baseline: 1.0490x; 1.0490x over previous
//
#include <hip/hip_runtime.h>
#include <hip/hip_bf16.h>

#define NLAYERS 6
#define Bc 2
#define Tc 13294
#define Ec 256
#define NHc 8
#define FFNc 1024

#define EPI_BIAS 0
#define EPI_MASK 1
#define EPI_RES  2
#define EPI_RELU 3
#define EPI_VALOA 4

typedef __attribute__((ext_vector_type(8))) short bf16x8;
typedef __attribute__((ext_vector_type(4))) float f32x4;

typedef __attribute__((address_space(3))) unsigned int u32_lds;
typedef __attribute__((address_space(1))) unsigned int u32_glb;

__device__ __forceinline__ void gld16(const void* g, void* l) {
    __builtin_amdgcn_global_load_lds((const u32_glb*)g, (u32_lds*)l, 16, 0, 0);
}

__device__ __forceinline__ short f2bf(float f) {
    union { float f; unsigned u; } v; v.f = f;
    unsigned r = v.u + 0x7FFFu + ((v.u >> 16) & 1u);
    return (short)(r >> 16);
}
__device__ __forceinline__ float bf2f(short s) {
    union { unsigned u; float f; } v; v.u = ((unsigned)(unsigned short)s) << 16;
    return v.f;
}
__device__ __forceinline__ float bf_lo(unsigned u) {
    union { unsigned u; float f; } v; v.u = u << 16; return v.f;
}

// ---------------- LayerNorm fp32-in (+ q = x + pos), bf16 outputs; layer 0 only ----------------
__global__ __launch_bounds__(256) void ln_kernel(
    const float* __restrict__ src, const float* __restrict__ pos,
    const float* __restrict__ g, const float* __restrict__ b,
    short* __restrict__ x, short* __restrict__ q, int rows)
{
    int wave = threadIdx.x >> 6;
    int lane = threadIdx.x & 63;
    int row = blockIdx.x * 4 + wave;
    if (row >= rows) return;
    const float* p = src + (size_t)row * Ec;
    float4 v = *(const float4*)(p + lane * 4);
    float s  = v.x + v.y + v.z + v.w;
    float sq = v.x*v.x + v.y*v.y + v.z*v.z + v.w*v.w;
    #pragma unroll
    for (int o = 32; o; o >>= 1) { s += __shfl_xor(s, o); sq += __shfl_xor(sq, o); }
    float mean = s * (1.f / Ec);
    float var  = sq * (1.f / Ec) - mean * mean;
    float inv  = rsqrtf(var + 1e-5f);
    float4 gg = *(const float4*)(g + lane * 4);
    float4 bb = *(const float4*)(b + lane * 4);
    float xo0 = (v.x - mean) * inv * gg.x + bb.x;
    float xo1 = (v.y - mean) * inv * gg.y + bb.y;
    float xo2 = (v.z - mean) * inv * gg.z + bb.z;
    float xo3 = (v.w - mean) * inv * gg.w + bb.w;
    short4 xs; xs.x = f2bf(xo0); xs.y = f2bf(xo1); xs.z = f2bf(xo2); xs.w = f2bf(xo3);
    *(short4*)(x + (size_t)row * Ec + lane * 4) = xs;
    float4 pp = *(const float4*)(pos + (size_t)row * Ec + lane * 4);
    short4 qs;
    qs.x = f2bf(xo0 + pp.x); qs.y = f2bf(xo1 + pp.y);
    qs.z = f2bf(xo2 + pp.z); qs.w = f2bf(xo3 + pp.w);
    *(short4*)(q + (size_t)row * Ec + lane * 4) = qs;
}

// ---------------- LayerNorm bf16-in, bf16 out (+ optional q = x + pos_fp32) ----------------
__global__ __launch_bounds__(256) void ln_bf_kernel(
    const short* __restrict__ src, const float* __restrict__ pos,
    const float* __restrict__ g, const float* __restrict__ b,
    short* __restrict__ x, short* __restrict__ q, int rows)
{
    int wave = threadIdx.x >> 6;
    int lane = threadIdx.x & 63;
    int row = blockIdx.x * 4 + wave;
    if (row >= rows) return;
    short4 v4 = *(const short4*)(src + (size_t)row * Ec + lane * 4);
    float v0 = bf2f(v4.x), v1 = bf2f(v4.y), v2 = bf2f(v4.z), v3 = bf2f(v4.w);
    float s  = v0 + v1 + v2 + v3;
    float sq = v0*v0 + v1*v1 + v2*v2 + v3*v3;
    #pragma unroll
    for (int o = 32; o; o >>= 1) { s += __shfl_xor(s, o); sq += __shfl_xor(sq, o); }
    float mean = s * (1.f / Ec);
    float var  = sq * (1.f / Ec) - mean * mean;
    float inv  = rsqrtf(var + 1e-5f);
    float4 gg = *(const float4*)(g + lane * 4);
    float4 bb = *(const float4*)(b + lane * 4);
    float xo0 = (v0 - mean) * inv * gg.x + bb.x;
    float xo1 = (v1 - mean) * inv * gg.y + bb.y;
    float xo2 = (v2 - mean) * inv * gg.z + bb.z;
    float xo3 = (v3 - mean) * inv * gg.w + bb.w;
    short4 xs; xs.x = f2bf(xo0); xs.y = f2bf(xo1); xs.z = f2bf(xo2); xs.w = f2bf(xo3);
    *(short4*)(x + (size_t)row * Ec + lane * 4) = xs;
    if (q) {
        float4 pp = *(const float4*)(pos + (size_t)row * Ec + lane * 4);
        short4 qs;
        qs.x = f2bf(xo0 + pp.x); qs.y = f2bf(xo1 + pp.y);
        qs.z = f2bf(xo2 + pp.z); qs.w = f2bf(xo3 + pp.w);
        *(short4*)(q + (size_t)row * Ec + lane * 4) = qs;
    }
}

// ---------------- merged weight transpose+convert: all 6 weights in one dispatch ----------------
__global__ __launch_bounds__(256) void transpose_all(
    const float* __restrict__ Wv,   const float* __restrict__ Woff,
    const float* __restrict__ Wattn,const float* __restrict__ Wout,
    const float* __restrict__ W1,   const float* __restrict__ W2,
    short* __restrict__ wcT, short* __restrict__ woutT,
    short* __restrict__ w1T, short* __restrict__ w2T)
{
    __shared__ float tile[32][33];
    const int l = blockIdx.z;
    const int t = blockIdx.x;
    const float* W; short* Wt; int K, N, lstr, rowOff, n0, k0;
    if (t < 64)       { W = Wv;    Wt = wcT;   K = 256;  N = 256;  lstr = 163840; rowOff = 0;
                        int u = t;        n0 = (u & 7) * 32;  k0 = (u >> 3) * 32; }
    else if (t < 128) { W = Woff;  Wt = wcT;   K = 256;  N = 256;  lstr = 163840; rowOff = 256;
                        int u = t - 64;   n0 = (u & 7) * 32;  k0 = (u >> 3) * 32; }
    else if (t < 160) { W = Wattn; Wt = wcT;   K = 256;  N = 128;  lstr = 163840; rowOff = 512;
                        int u = t - 128;  n0 = (u & 3) * 32;  k0 = (u >> 2) * 32; }
    else if (t < 224) { W = Wout;  Wt = woutT; K = 256;  N = 256;  lstr = 65536;  rowOff = 0;
                        int u = t - 160;  n0 = (u & 7) * 32;  k0 = (u >> 3) * 32; }
    else if (t < 480) { W = W1;    Wt = w1T;   K = 256;  N = 1024; lstr = 262144; rowOff = 0;
                        int u = t - 224;  n0 = (u & 31) * 32; k0 = (u >> 5) * 32; }
    else              { W = W2;    Wt = w2T;   K = 1024; N = 256;  lstr = 262144; rowOff = 0;
                        int u = t - 480;  n0 = (u & 7) * 32;  k0 = (u >> 3) * 32; }
    const float* Wl = W + (size_t)l * K * N;
    short* Wtl = Wt + (size_t)l * lstr;
    int tx = threadIdx.x & 31, ty = threadIdx.x >> 5;
    #pragma unroll
    for (int i = 0; i < 32; i += 8)
        tile[ty + i][tx] = Wl[(size_t)(k0 + ty + i) * N + n0 + tx];
    __syncthreads();
    #pragma unroll
    for (int i = 0; i < 32; i += 8)
        Wtl[(size_t)(rowOff + n0 + ty + i) * K + k0 + tx] = f2bf(tile[tx][ty + i]);
}

// ---------------- bf16 MFMA GEMM: 128x64 tile, BK=32, double-buffered LDS ----------------
// (R12 structure: 2-phase, STAGE(t+1) before compute(t), single barrier drain per iter —
// measured best; 128x128 / 32x32-MFMA / 3-deep counted-vmcnt all neutral-or-worse.)
// EPI_VALOA: A2 used for col>=256 blocks; outputs split: col<256 -> Cout2 (valb, stride 256,
// mask), col>=256 -> Cout (oab, stride 384, col-256), biases bias/bias2/bias3 per segment.
template<int EPI, int OBF, int RESBF>
__global__ __launch_bounds__(256) void gemm_mfma(
    const short* __restrict__ A, const short* __restrict__ A2,
    const short* __restrict__ Bt,
    const float* __restrict__ bias, const float* __restrict__ bias2,
    const float* __restrict__ bias3,
    const float* __restrict__ resf, const short* __restrict__ resb,
    const unsigned char* __restrict__ mask,
    void* __restrict__ Cout, void* __restrict__ Cout2, int M, int N, int K)
{
    __shared__ short As[2][128 * 32];
    __shared__ short Bs[2][64 * 32];
    const int tid = threadIdx.x;
    const int lane = tid & 63;
    const int wv = tid >> 6;
    const int row0 = blockIdx.x * 128;
    const int col0 = blockIdx.y * 64;
    const int mbase = (wv >> 1) * 64;   // wave tile: 64 rows x 32 cols
    const int nbase = (wv & 1) * 32;
    const int lr = lane & 15;
    const int kg = lane >> 4;

    const short* Ause = (EPI == EPI_VALOA && blockIdx.y >= 4) ? A2 : A;

    f32x4 zf = {0.f, 0.f, 0.f, 0.f};
    f32x4 acc[4][2];
    #pragma unroll
    for (int i = 0; i < 4; ++i)
        #pragma unroll
        for (int j = 0; j < 2; ++j) acc[i][j] = zf;

    const int scol = (lane & 3) * 8;
    const int srowA = wv * 32 + (lane >> 2);
    const short* Ap = Ause + (size_t)(row0 + srowA) * K + scol;
    const int lA0 = srowA * 32 + scol;
    const int lA1 = lA0 + 16 * 32;
    const int srowB = wv * 16 + (lane >> 2);
    const short* Bp = Bt + (size_t)(col0 + srowB) * K + scol;
    const int lB = srowB * 32 + scol;

    #define STAGE(buf, k0) do { \
        gld16(Ap + (k0),                &As[buf][lA0]); \
        gld16(Ap + (size_t)16*K + (k0), &As[buf][lA1]); \
        gld16(Bp + (k0),                &Bs[buf][lB]); \
    } while (0)

    STAGE(0, 0);
    __syncthreads();
    int cur = 0;
    for (int k0 = 0; k0 < K; k0 += 32) {
        if (k0 + 32 < K) STAGE(cur ^ 1, k0 + 32);
        bf16x8 af[4], bfr[2];
        #pragma unroll
        for (int i = 0; i < 4; ++i)
            af[i]  = *(const bf16x8*)&As[cur][(mbase + i * 16 + lr) * 32 + kg * 8];
        #pragma unroll
        for (int j = 0; j < 2; ++j)
            bfr[j] = *(const bf16x8*)&Bs[cur][(nbase + j * 16 + lr) * 32 + kg * 8];
        #pragma unroll
        for (int mi = 0; mi < 4; ++mi)
            #pragma unroll
            for (int ni = 0; ni < 2; ++ni)
                acc[mi][ni] = __builtin_amdgcn_mfma_f32_16x16x32_bf16(
                    af[mi], bfr[ni], acc[mi][ni], 0, 0, 0);
        __syncthreads();
        cur ^= 1;
    }
    #undef STAGE

    float* Cf = (float*)Cout;
    short* Cb = (short*)Cout;
    short* Vb = (short*)Cout2;
    #pragma unroll
    for (int ni = 0; ni < 2; ++ni) {
        int col = col0 + nbase + ni * 16 + lr;
        float bz;
        if (EPI == EPI_VALOA)
            bz = (col < 256) ? bias[col] : ((col < 512) ? bias2[col - 256] : bias3[col - 512]);
        else
            bz = (bias2 && col >= 256) ? bias2[col - 256] : bias[col];
        #pragma unroll
        for (int mi = 0; mi < 4; ++mi) {
            int rb = row0 + mbase + mi * 16 + kg * 4;
            #pragma unroll
            for (int j = 0; j < 4; ++j) {
                int grow = rb + j;
                if (grow >= M) continue;
                float v = acc[mi][ni][j] + bz;
                if (EPI == EPI_VALOA) {
                    if (col < 256) {
                        if (mask[grow]) v = 0.f;
                        Vb[(size_t)grow * 256 + col] = f2bf(v);
                    } else {
                        Cb[(size_t)grow * 384 + (col - 256)] = f2bf(v);
                    }
                    continue;
                }
                if (EPI == EPI_MASK) { if (mask[grow]) v = 0.f; }
                if (EPI == EPI_RES) {
                    v += RESBF ? bf2f(resb[(size_t)grow * N + col])
                               : resf[(size_t)grow * N + col];
                }
                if (EPI == EPI_RELU) v = v > 0.f ? v : 0.f;
                if (OBF) Cb[(size_t)grow * N + col] = f2bf(v);
                else     Cf[(size_t)grow * N + col] = v;
            }
        }
    }
}

// ---------------- MSDA with fused softmax; value + oa bf16 ----------------
// block = one bq (all 8 heads); phase-1 compacted onto threads 0..127 (2 full waves);
// phase-2: 32-lane group per head; lane owns 2 dims (dword, 16 lanes/64B row).
// pts layout conflict-free ({0,4,8,12} bank starts).
// phase-1 algebra: xf = (refx + ox/w)*w - 0.5 == refx*w + ox - 0.5  (kills 2 divides);
// softmax normalization via rcp.
__global__ __launch_bounds__(256) void msda_kernel(
    const short* __restrict__ value, const short* __restrict__ oa,
    const float* __restrict__ vr, short* __restrict__ out)
{
    __shared__ int pts[8 * 136];
    const int t = threadIdx.x;
    const int bq = blockIdx.x;
    const int b = (bq >= Tc) ? 1 : 0;
    const int qq = bq - b * Tc;

    if (t < 128) {
        const int g = t >> 4;        // group == head
        const int p = t & 15;
        const int lvl = p >> 2;
        const int St[4] = {0, 10000, 12500, 13125};
        int qi, Wq, qlvl;
        if (qq < 10000)      { qlvl = 0; qi = qq;         Wq = 100; }
        else if (qq < 12500) { qlvl = 1; qi = qq - 10000; Wq = 50; }
        else if (qq < 13125) { qlvl = 2; qi = qq - 12500; Wq = 25; }
        else                 { qlvl = 3; qi = qq - 13125; Wq = 13; }
        float base_x = (0.5f + (float)(qi % Wq)) / (vr[(b*4+qlvl)*2+0] * (float)Wq);
        float base_y = (0.5f + (float)(qi / Wq)) / (vr[(b*4+qlvl)*2+1] * (float)Wq);

        // softmax over 16 logits (one per lane; 16-lane group is wave-aligned)
        float logit = bf2f(oa[(size_t)bq * 384 + 256 + g * 16 + p]);
        float mx = logit;
        #pragma unroll
        for (int o = 8; o; o >>= 1) mx = fmaxf(mx, __shfl_xor(mx, o));
        float e = __expf(logit - mx);
        float sum = e;
        #pragma unroll
        for (int o = 8; o; o >>= 1) sum += __shfl_xor(sum, o);
        float aw = e * __frcp_rn(sum);

        const int w = (lvl == 0) ? 100 : ((lvl == 1) ? 50 : ((lvl == 2) ? 25 : 13));
        const int hh = w;
        const float wf = (float)w;
        const float refxw = base_x * vr[(b*4+lvl)*2+0] * wf;
        const float refyw = base_y * vr[(b*4+lvl)*2+1] * wf;
        const float ox = bf2f(oa[(size_t)bq * 384 + g * 32 + p * 2 + 0]);
        const float oy = bf2f(oa[(size_t)bq * 384 + g * 32 + p * 2 + 1]);
        float xf = refxw + ox - 0.5f;
        float yf = refyw + oy - 0.5f;
        float x0f = floorf(xf), y0f = floorf(yf);
        int x0 = (int)x0f, y0 = (int)y0f;
        float wx = xf - x0f, wy = yf - y0f;
        float w00 = (1.f - wx) * (1.f - wy) * aw;
        float w10 = wx * (1.f - wy) * aw;
        float w01 = (1.f - wx) * wy * aw;
        float w11 = wx * wy * aw;
        bool vx0 = (x0 >= 0) && (x0 < w);
        bool vx1 = (x0 + 1 >= 0) && (x0 + 1 < w);
        bool vy0 = (y0 >= 0) && (y0 < hh);
        bool vy1 = (y0 + 1 >= 0) && (y0 + 1 < hh);
        if (!(vx0 && vy0)) w00 = 0.f;
        if (!(vx1 && vy0)) w10 = 0.f;
        if (!(vx0 && vy1)) w01 = 0.f;
        if (!(vx1 && vy1)) w11 = 0.f;
        int cx0 = min(max(x0, 0), w - 1), cx1 = min(max(x0 + 1, 0), w - 1);
        int cy0 = min(max(y0, 0), hh - 1), cy1 = min(max(y0 + 1, 0), hh - 1);
        int rowbase = b * Tc + St[lvl];
        int slot = g * 136 + p * 8 + ((p >> 3) & 1) * 4;
        int4 wq4; wq4.x = __float_as_int(w00); wq4.y = __float_as_int(w10);
        wq4.z = __float_as_int(w01); wq4.w = __float_as_int(w11);
        int4 aq4;
        aq4.x = (rowbase + cy0 * w + cx0) * 512 + g * 64;
        aq4.y = (rowbase + cy0 * w + cx1) * 512 + g * 64;
        aq4.z = (rowbase + cy1 * w + cx0) * 512 + g * 64;
        aq4.w = (rowbase + cy1 * w + cx1) * 512 + g * 64;
        *(int4*)&pts[slot] = wq4;
        *(int4*)&pts[slot + 4] = aq4;
    }
    __syncthreads();

    const int group = t >> 5;               // head
    const int l32 = t & 31;
    const int d4 = (l32 & 15) * 4;
    const int ph = (l32 >> 4) * 8;
    const int xw = (l32 >> 4) * 4;
    const char* vbase = (const char*)value;
    float accL = 0.f, accH = 0.f;
    #pragma unroll
    for (int j = 0; j < 8; ++j) {
        int p = ph + j;
        int slot = group * 136 + p * 8 + xw;
        int4 wq = *(const int4*)&pts[slot];
        int4 aq = *(const int4*)&pts[slot + 4];
        unsigned u0 = *(const unsigned*)(vbase + (unsigned)(aq.x + d4));
        unsigned u1 = *(const unsigned*)(vbase + (unsigned)(aq.y + d4));
        unsigned u2 = *(const unsigned*)(vbase + (unsigned)(aq.z + d4));
        unsigned u3 = *(const unsigned*)(vbase + (unsigned)(aq.w + d4));
        float w00 = __int_as_float(wq.x), w10 = __int_as_float(wq.y);
        float w01 = __int_as_float(wq.z), w11 = __int_as_float(wq.w);
        // hi half: raw reinterpret (garbage low mantissa bits << bf16 rounding error)
        accL = fmaf(w00, bf_lo(u0), accL); accH = fmaf(w00, __int_as_float((int)u0), accH);
        accL = fmaf(w10, bf_lo(u1), accL); accH = fmaf(w10, __int_as_float((int)u1), accH);
        accL = fmaf(w01, bf_lo(u2), accL); accH = fmaf(w01, __int_as_float((int)u2), accH);
        accL = fmaf(w11, bf_lo(u3), accL); accH = fmaf(w11, __int_as_float((int)u3), accH);
    }
    accL += __shfl_xor(accL, 16);
    accH += __shfl_xor(accH, 16);
    if (l32 < 16) {
        unsigned pk = ((unsigned)(unsigned short)f2bf(accL)) |
                      (((unsigned)(unsigned short)f2bf(accH)) << 16);
        *(unsigned*)((char*)out + (size_t)bq * 512 + group * 64 + d4) = pk;
    }
}

extern "C" void kernel_launch(void* const* d_in, const int* in_sizes, int n_in,
                              void* d_out, int out_size, void* d_ws, size_t ws_size,
                              hipStream_t stream) {
    const float* src  = (const float*)d_in[0];
    const float* pos  = (const float*)d_in[1];
    const float* vr   = (const float*)d_in[2];
    const unsigned char* mask = (const unsigned char*)d_in[5];
    const float* Wv    = (const float*)d_in[6];
    const float* bv    = (const float*)d_in[7];
    const float* Woff  = (const float*)d_in[8];
    const float* boff  = (const float*)d_in[9];
    const float* Wattn = (const float*)d_in[10];
    const float* battn = (const float*)d_in[11];
    const float* Wout  = (const float*)d_in[12];
    const float* bout  = (const float*)d_in[13];
    const float* n1g   = (const float*)d_in[14];
    const float* n1b   = (const float*)d_in[15];
    const float* n2g   = (const float*)d_in[16];
    const float* n2b   = (const float*)d_in[17];
    const float* W1    = (const float*)d_in[18];
    const float* b1    = (const float*)d_in[19];
    const float* W2    = (const float*)d_in[20];
    const float* b2    = (const float*)d_in[21];
    float* out = (float*)d_out;

    const size_t R = (size_t)Bc * Tc;   // 26588

    // shorts/row: xb 256 | qb 256 | valb 256 | msdab 256 | oab 384 | srcb 256
    short* xb    = (short*)d_ws;
    short* qb    = xb + R * 256;
    short* valb  = qb + R * 256;
    short* msdab = valb + R * 256;
    short* oab   = msdab + R * 256;           // R*384
    short* srcb  = oab + R * 384;             // R*256 bf16 residual stream
    short* ln2b  = xb;                        // alias: xb dead by LN2 time
    short* hb    = qb;                        // alias: qb..oab >= R*1024, dead by ffn1
    short* wcT   = srcb + R * 256;            // 6*163840 ([640][256]: Wv|Woff|Wattn)
    short* woutT = wcT + 6 * 163840;          // 6*65536
    short* w1T   = woutT + 6 * 65536;         // 6*262144 ([1024][256])
    short* w2T   = w1T + 6 * 262144;          // 6*262144 ([256][1024])

    // one-time setup: all weight transposes in a single dispatch
    transpose_all<<<dim3(736, 1, 6), 256, 0, stream>>>(
        Wv, Woff, Wattn, Wout, W1, W2, wcT, woutT, w1T, w2T);

    const int M = (int)R;
    const int lnBlocks = (int)((R + 3) / 4);
    const int MT = (int)((R + 127) / 128);  // 208

    // layer 0 LN1 (fp32 src input)
    ln_kernel<<<lnBlocks, 256, 0, stream>>>(src, pos, n1g, n1b, xb, qb, M);

    for (int l = 0; l < NLAYERS; ++l) {
        // merged: [value | off | logits]; A = xb for cols<256, qb otherwise
        gemm_mfma<EPI_VALOA, 1, 0><<<dim3(MT, 10), 256, 0, stream>>>(
            xb, qb, wcT + (size_t)l * 163840, bv + l * Ec, boff + l * 256, battn + l * 128,
            nullptr, nullptr, mask, oab, valb, M, 640, 256);
        // MSDA (softmax fused) -> bf16
        msda_kernel<<<(int)R, 256, 0, stream>>>(valb, oab, vr, msdab);
        // src2 = cur + msda @ Wout + bout -> bf16 srcb
        if (l == 0)
            gemm_mfma<EPI_RES, 1, 0><<<dim3(MT, 4), 256, 0, stream>>>(
                msdab, nullptr, woutT + (size_t)l * 65536, bout + l * Ec, nullptr, nullptr,
                src, nullptr, nullptr, srcb, nullptr, M, 256, 256);
        else
            gemm_mfma<EPI_RES, 1, 1><<<dim3(MT, 4), 256, 0, stream>>>(
                msdab, nullptr, woutT + (size_t)l * 65536, bout + l * Ec, nullptr, nullptr,
                nullptr, srcb, nullptr, srcb, nullptr, M, 256, 256);
        // LN2 (bf16 in/out) -> ln2b
        ln_bf_kernel<<<lnBlocks, 256, 0, stream>>>(srcb, nullptr, n2g + l * Ec, n2b + l * Ec,
                                                   ln2b, nullptr, M);
        // h = relu(ln2 @ W1 + b1) -> bf16
        gemm_mfma<EPI_RELU, 1, 0><<<dim3(MT, 16), 256, 0, stream>>>(
            ln2b, nullptr, w1T + (size_t)l * 262144, b1 + l * FFNc, nullptr, nullptr,
            nullptr, nullptr, nullptr, hb, nullptr, M, 1024, 256);
        // src = src2 + h @ W2 + b2 ; last layer -> fp32 out, else bf16 srcb
        if (l < NLAYERS - 1) {
            gemm_mfma<EPI_RES, 1, 1><<<dim3(MT, 4), 256, 0, stream>>>(
                hb, nullptr, w2T + (size_t)l * 262144, b2 + l * Ec, nullptr, nullptr,
                nullptr, srcb, nullptr, srcb, nullptr, M, 256, 1024);
            // next-layer LN1 (+ q = x + pos, pos read fp32)
            ln_bf_kernel<<<lnBlocks, 256, 0, stream>>>(srcb, pos, n1g + (l + 1) * Ec,
                                                       n1b + (l + 1) * Ec, xb, qb, M);
        } else {
            gemm_mfma<EPI_RES, 0, 1><<<dim3(MT, 4), 256, 0, stream>>>(
                hb, nullptr, w2T + (size_t)l * 262144, b2 + l * Ec, nullptr, nullptr,
                nullptr, srcb, nullptr, out, nullptr, M, 256, 1024);
        }
    }
}

// Round 15
// 1057.278 us; speedup vs baseline: 1.1230x; 1.0705x over previous
//
#include <hip/hip_runtime.h>
#include <hip/hip_bf16.h>

#define NLAYERS 6
#define Bc 2
#define Tc 13294
#define Ec 256
#define NHc 8
#define FFNc 1024

#define EPI_BIAS 0
#define EPI_MASK 1
#define EPI_RES  2
#define EPI_RELU 3
#define EPI_VALOA 4

typedef __attribute__((ext_vector_type(8))) short bf16x8;
typedef __attribute__((ext_vector_type(4))) float f32x4;

typedef __attribute__((address_space(3))) unsigned int u32_lds;
typedef __attribute__((address_space(1))) unsigned int u32_glb;

__device__ __forceinline__ void gld16(const void* g, void* l) {
    __builtin_amdgcn_global_load_lds((const u32_glb*)g, (u32_lds*)l, 16, 0, 0);
}

__device__ __forceinline__ short f2bf(float f) {
    union { float f; unsigned u; } v; v.f = f;
    unsigned r = v.u + 0x7FFFu + ((v.u >> 16) & 1u);
    return (short)(r >> 16);
}
__device__ __forceinline__ float bf2f(short s) {
    union { unsigned u; float f; } v; v.u = ((unsigned)(unsigned short)s) << 16;
    return v.f;
}
__device__ __forceinline__ float bf_lo(unsigned u) {
    union { unsigned u; float f; } v; v.u = u << 16; return v.f;
}

// ---------------- LayerNorm fp32-in (+ q = x + pos), bf16 outputs; layer 0 only ----------------
__global__ __launch_bounds__(256) void ln_kernel(
    const float* __restrict__ src, const float* __restrict__ pos,
    const float* __restrict__ g, const float* __restrict__ b,
    short* __restrict__ x, short* __restrict__ q, int rows)
{
    int wave = threadIdx.x >> 6;
    int lane = threadIdx.x & 63;
    int row = blockIdx.x * 4 + wave;
    if (row >= rows) return;
    const float* p = src + (size_t)row * Ec;
    float4 v = *(const float4*)(p + lane * 4);
    float s  = v.x + v.y + v.z + v.w;
    float sq = v.x*v.x + v.y*v.y + v.z*v.z + v.w*v.w;
    #pragma unroll
    for (int o = 32; o; o >>= 1) { s += __shfl_xor(s, o); sq += __shfl_xor(sq, o); }
    float mean = s * (1.f / Ec);
    float var  = sq * (1.f / Ec) - mean * mean;
    float inv  = rsqrtf(var + 1e-5f);
    float4 gg = *(const float4*)(g + lane * 4);
    float4 bb = *(const float4*)(b + lane * 4);
    float xo0 = (v.x - mean) * inv * gg.x + bb.x;
    float xo1 = (v.y - mean) * inv * gg.y + bb.y;
    float xo2 = (v.z - mean) * inv * gg.z + bb.z;
    float xo3 = (v.w - mean) * inv * gg.w + bb.w;
    short4 xs; xs.x = f2bf(xo0); xs.y = f2bf(xo1); xs.z = f2bf(xo2); xs.w = f2bf(xo3);
    *(short4*)(x + (size_t)row * Ec + lane * 4) = xs;
    float4 pp = *(const float4*)(pos + (size_t)row * Ec + lane * 4);
    short4 qs;
    qs.x = f2bf(xo0 + pp.x); qs.y = f2bf(xo1 + pp.y);
    qs.z = f2bf(xo2 + pp.z); qs.w = f2bf(xo3 + pp.w);
    *(short4*)(q + (size_t)row * Ec + lane * 4) = qs;
}

// ---------------- LayerNorm bf16-in, bf16 out (+ optional q = x + pos_fp32) ----------------
__global__ __launch_bounds__(256) void ln_bf_kernel(
    const short* __restrict__ src, const float* __restrict__ pos,
    const float* __restrict__ g, const float* __restrict__ b,
    short* __restrict__ x, short* __restrict__ q, int rows)
{
    int wave = threadIdx.x >> 6;
    int lane = threadIdx.x & 63;
    int row = blockIdx.x * 4 + wave;
    if (row >= rows) return;
    short4 v4 = *(const short4*)(src + (size_t)row * Ec + lane * 4);
    float v0 = bf2f(v4.x), v1 = bf2f(v4.y), v2 = bf2f(v4.z), v3 = bf2f(v4.w);
    float s  = v0 + v1 + v2 + v3;
    float sq = v0*v0 + v1*v1 + v2*v2 + v3*v3;
    #pragma unroll
    for (int o = 32; o; o >>= 1) { s += __shfl_xor(s, o); sq += __shfl_xor(sq, o); }
    float mean = s * (1.f / Ec);
    float var  = sq * (1.f / Ec) - mean * mean;
    float inv  = rsqrtf(var + 1e-5f);
    float4 gg = *(const float4*)(g + lane * 4);
    float4 bb = *(const float4*)(b + lane * 4);
    float xo0 = (v0 - mean) * inv * gg.x + bb.x;
    float xo1 = (v1 - mean) * inv * gg.y + bb.y;
    float xo2 = (v2 - mean) * inv * gg.z + bb.z;
    float xo3 = (v3 - mean) * inv * gg.w + bb.w;
    short4 xs; xs.x = f2bf(xo0); xs.y = f2bf(xo1); xs.z = f2bf(xo2); xs.w = f2bf(xo3);
    *(short4*)(x + (size_t)row * Ec + lane * 4) = xs;
    if (q) {
        float4 pp = *(const float4*)(pos + (size_t)row * Ec + lane * 4);
        short4 qs;
        qs.x = f2bf(xo0 + pp.x); qs.y = f2bf(xo1 + pp.y);
        qs.z = f2bf(xo2 + pp.z); qs.w = f2bf(xo3 + pp.w);
        *(short4*)(q + (size_t)row * Ec + lane * 4) = qs;
    }
}

// ---------------- merged weight transpose+convert: all 6 weights in one dispatch ----------------
__global__ __launch_bounds__(256) void transpose_all(
    const float* __restrict__ Wv,   const float* __restrict__ Woff,
    const float* __restrict__ Wattn,const float* __restrict__ Wout,
    const float* __restrict__ W1,   const float* __restrict__ W2,
    short* __restrict__ wcT, short* __restrict__ woutT,
    short* __restrict__ w1T, short* __restrict__ w2T)
{
    __shared__ float tile[32][33];
    const int l = blockIdx.z;
    const int t = blockIdx.x;
    const float* W; short* Wt; int K, N, lstr, rowOff, n0, k0;
    if (t < 64)       { W = Wv;    Wt = wcT;   K = 256;  N = 256;  lstr = 163840; rowOff = 0;
                        int u = t;        n0 = (u & 7) * 32;  k0 = (u >> 3) * 32; }
    else if (t < 128) { W = Woff;  Wt = wcT;   K = 256;  N = 256;  lstr = 163840; rowOff = 256;
                        int u = t - 64;   n0 = (u & 7) * 32;  k0 = (u >> 3) * 32; }
    else if (t < 160) { W = Wattn; Wt = wcT;   K = 256;  N = 128;  lstr = 163840; rowOff = 512;
                        int u = t - 128;  n0 = (u & 3) * 32;  k0 = (u >> 2) * 32; }
    else if (t < 224) { W = Wout;  Wt = woutT; K = 256;  N = 256;  lstr = 65536;  rowOff = 0;
                        int u = t - 160;  n0 = (u & 7) * 32;  k0 = (u >> 3) * 32; }
    else if (t < 480) { W = W1;    Wt = w1T;   K = 256;  N = 1024; lstr = 262144; rowOff = 0;
                        int u = t - 224;  n0 = (u & 31) * 32; k0 = (u >> 5) * 32; }
    else              { W = W2;    Wt = w2T;   K = 1024; N = 256;  lstr = 262144; rowOff = 0;
                        int u = t - 480;  n0 = (u & 7) * 32;  k0 = (u >> 3) * 32; }
    const float* Wl = W + (size_t)l * K * N;
    short* Wtl = Wt + (size_t)l * lstr;
    int tx = threadIdx.x & 31, ty = threadIdx.x >> 5;
    #pragma unroll
    for (int i = 0; i < 32; i += 8)
        tile[ty + i][tx] = Wl[(size_t)(k0 + ty + i) * N + n0 + tx];
    __syncthreads();
    #pragma unroll
    for (int i = 0; i < 32; i += 8)
        Wtl[(size_t)(rowOff + n0 + ty + i) * K + k0 + tx] = f2bf(tile[tx][ty + i]);
}

// ---------------- bf16 MFMA GEMM: 128x64 tile, BK=32, double-buffered LDS ----------------
// R12 loop structure (measured best). NEW: MFMA operands swapped -> acc holds C^T fragments:
// per lane, M-row = tile_base + (lane&15) FIXED, and each (mi,ni,reg) gives 4 CONSECUTIVE
// N-cols at nbase+ni*16+(lane>>4)*4. Epilogue: packed short4/float4 stores (4x fewer store
// instrs than scalar bf16), vector bias/residual loads. Arithmetic bit-identical.
// EPI_VALOA: A2 for col>=256 blocks; out col<256 -> Cout2 (valb, mask), col>=256 -> Cout
// (oab stride 384); biases bias/bias2/bias3 per 256/256/128 segment (4-col packs are
// 4-aligned so they never straddle segment boundaries).
template<int EPI, int OBF, int RESBF>
__global__ __launch_bounds__(256) void gemm_mfma(
    const short* __restrict__ A, const short* __restrict__ A2,
    const short* __restrict__ Bt,
    const float* __restrict__ bias, const float* __restrict__ bias2,
    const float* __restrict__ bias3,
    const float* __restrict__ resf, const short* __restrict__ resb,
    const unsigned char* __restrict__ mask,
    void* __restrict__ Cout, void* __restrict__ Cout2, int M, int N, int K)
{
    __shared__ short As[2][128 * 32];
    __shared__ short Bs[2][64 * 32];
    const int tid = threadIdx.x;
    const int lane = tid & 63;
    const int wv = tid >> 6;
    const int row0 = blockIdx.x * 128;
    const int col0 = blockIdx.y * 64;
    const int mbase = (wv >> 1) * 64;   // wave tile: 64 rows x 32 cols
    const int nbase = (wv & 1) * 32;
    const int lr = lane & 15;
    const int kg = lane >> 4;

    const short* Ause = (EPI == EPI_VALOA && blockIdx.y >= 4) ? A2 : A;

    f32x4 zf = {0.f, 0.f, 0.f, 0.f};
    f32x4 acc[4][2];
    #pragma unroll
    for (int i = 0; i < 4; ++i)
        #pragma unroll
        for (int j = 0; j < 2; ++j) acc[i][j] = zf;

    const int scol = (lane & 3) * 8;
    const int srowA = wv * 32 + (lane >> 2);
    const short* Ap = Ause + (size_t)(row0 + srowA) * K + scol;
    const int lA0 = srowA * 32 + scol;
    const int lA1 = lA0 + 16 * 32;
    const int srowB = wv * 16 + (lane >> 2);
    const short* Bp = Bt + (size_t)(col0 + srowB) * K + scol;
    const int lB = srowB * 32 + scol;

    #define STAGE(buf, k0) do { \
        gld16(Ap + (k0),                &As[buf][lA0]); \
        gld16(Ap + (size_t)16*K + (k0), &As[buf][lA1]); \
        gld16(Bp + (k0),                &Bs[buf][lB]); \
    } while (0)

    STAGE(0, 0);
    __syncthreads();
    int cur = 0;
    for (int k0 = 0; k0 < K; k0 += 32) {
        if (k0 + 32 < K) STAGE(cur ^ 1, k0 + 32);
        bf16x8 af[4], bfr[2];
        #pragma unroll
        for (int i = 0; i < 4; ++i)
            af[i]  = *(const bf16x8*)&As[cur][(mbase + i * 16 + lr) * 32 + kg * 8];
        #pragma unroll
        for (int j = 0; j < 2; ++j)
            bfr[j] = *(const bf16x8*)&Bs[cur][(nbase + j * 16 + lr) * 32 + kg * 8];
        // operand swap: D = B^T-fragment x A-fragment -> C^T lane layout
        #pragma unroll
        for (int mi = 0; mi < 4; ++mi)
            #pragma unroll
            for (int ni = 0; ni < 2; ++ni)
                acc[mi][ni] = __builtin_amdgcn_mfma_f32_16x16x32_bf16(
                    bfr[ni], af[mi], acc[mi][ni], 0, 0, 0);
        __syncthreads();
        cur ^= 1;
    }
    #undef STAGE

    // epilogue: per lane, row = row0+mbase+mi*16+lr; cols = col0+nbase+ni*16+kg*4 .. +3
    float* Cf = (float*)Cout;
    short* Cb = (short*)Cout;
    short* Vb = (short*)Cout2;
    #pragma unroll
    for (int ni = 0; ni < 2; ++ni) {
        const int colb = col0 + nbase + ni * 16 + kg * 4;   // 4 consecutive cols
        float4 bz4;
        if (EPI == EPI_VALOA) {
            const float* bp = (colb < 256) ? (bias + colb)
                             : ((colb < 512) ? (bias2 + colb - 256) : (bias3 + colb - 512));
            bz4 = *(const float4*)bp;
        } else {
            bz4 = *(const float4*)(bias + colb);
        }
        #pragma unroll
        for (int mi = 0; mi < 4; ++mi) {
            int grow = row0 + mbase + mi * 16 + lr;
            if (grow >= M) continue;
            float v0 = acc[mi][ni][0] + bz4.x;
            float v1 = acc[mi][ni][1] + bz4.y;
            float v2 = acc[mi][ni][2] + bz4.z;
            float v3 = acc[mi][ni][3] + bz4.w;
            if (EPI == EPI_VALOA) {
                if (colb < 256) {
                    if (mask[grow]) { v0 = 0.f; v1 = 0.f; v2 = 0.f; v3 = 0.f; }
                    short4 s; s.x = f2bf(v0); s.y = f2bf(v1); s.z = f2bf(v2); s.w = f2bf(v3);
                    *(short4*)(Vb + (size_t)grow * 256 + colb) = s;
                } else {
                    short4 s; s.x = f2bf(v0); s.y = f2bf(v1); s.z = f2bf(v2); s.w = f2bf(v3);
                    *(short4*)(Cb + (size_t)grow * 384 + (colb - 256)) = s;
                }
                continue;
            }
            if (EPI == EPI_RES) {
                if (RESBF) {
                    short4 r = *(const short4*)(resb + (size_t)grow * N + colb);
                    v0 += bf2f(r.x); v1 += bf2f(r.y); v2 += bf2f(r.z); v3 += bf2f(r.w);
                } else {
                    float4 r = *(const float4*)(resf + (size_t)grow * N + colb);
                    v0 += r.x; v1 += r.y; v2 += r.z; v3 += r.w;
                }
            }
            if (EPI == EPI_RELU) {
                v0 = v0 > 0.f ? v0 : 0.f; v1 = v1 > 0.f ? v1 : 0.f;
                v2 = v2 > 0.f ? v2 : 0.f; v3 = v3 > 0.f ? v3 : 0.f;
            }
            if (OBF) {
                short4 s; s.x = f2bf(v0); s.y = f2bf(v1); s.z = f2bf(v2); s.w = f2bf(v3);
                *(short4*)(Cb + (size_t)grow * N + colb) = s;
            } else {
                float4 s; s.x = v0; s.y = v1; s.z = v2; s.w = v3;
                *(float4*)(Cf + (size_t)grow * N + colb) = s;
            }
        }
    }
}

// ---------------- MSDA with fused softmax; value + oa bf16 ----------------
// block = one bq (all 8 heads); phase-1 compacted onto threads 0..127 (2 full waves);
// phase-2: 32-lane group per head; lane owns 2 dims (dword, 16 lanes/64B row).
// pts layout conflict-free ({0,4,8,12} bank starts).
__global__ __launch_bounds__(256) void msda_kernel(
    const short* __restrict__ value, const short* __restrict__ oa,
    const float* __restrict__ vr, short* __restrict__ out)
{
    __shared__ int pts[8 * 136];
    const int t = threadIdx.x;
    const int bq = blockIdx.x;
    const int b = (bq >= Tc) ? 1 : 0;
    const int qq = bq - b * Tc;

    if (t < 128) {
        const int g = t >> 4;        // group == head
        const int p = t & 15;
        const int lvl = p >> 2;
        const int St[4] = {0, 10000, 12500, 13125};
        int qi, Wq, qlvl;
        if (qq < 10000)      { qlvl = 0; qi = qq;         Wq = 100; }
        else if (qq < 12500) { qlvl = 1; qi = qq - 10000; Wq = 50; }
        else if (qq < 13125) { qlvl = 2; qi = qq - 12500; Wq = 25; }
        else                 { qlvl = 3; qi = qq - 13125; Wq = 13; }
        float base_x = (0.5f + (float)(qi % Wq)) / (vr[(b*4+qlvl)*2+0] * (float)Wq);
        float base_y = (0.5f + (float)(qi / Wq)) / (vr[(b*4+qlvl)*2+1] * (float)Wq);

        // softmax over 16 logits (one per lane; 16-lane group is wave-aligned)
        float logit = bf2f(oa[(size_t)bq * 384 + 256 + g * 16 + p]);
        float mx = logit;
        #pragma unroll
        for (int o = 8; o; o >>= 1) mx = fmaxf(mx, __shfl_xor(mx, o));
        float e = __expf(logit - mx);
        float sum = e;
        #pragma unroll
        for (int o = 8; o; o >>= 1) sum += __shfl_xor(sum, o);
        float aw = e * __frcp_rn(sum);

        const int w = (lvl == 0) ? 100 : ((lvl == 1) ? 50 : ((lvl == 2) ? 25 : 13));
        const int hh = w;
        const float wf = (float)w;
        const float refxw = base_x * vr[(b*4+lvl)*2+0] * wf;
        const float refyw = base_y * vr[(b*4+lvl)*2+1] * wf;
        const float ox = bf2f(oa[(size_t)bq * 384 + g * 32 + p * 2 + 0]);
        const float oy = bf2f(oa[(size_t)bq * 384 + g * 32 + p * 2 + 1]);
        float xf = refxw + ox - 0.5f;
        float yf = refyw + oy - 0.5f;
        float x0f = floorf(xf), y0f = floorf(yf);
        int x0 = (int)x0f, y0 = (int)y0f;
        float wx = xf - x0f, wy = yf - y0f;
        float w00 = (1.f - wx) * (1.f - wy) * aw;
        float w10 = wx * (1.f - wy) * aw;
        float w01 = (1.f - wx) * wy * aw;
        float w11 = wx * wy * aw;
        bool vx0 = (x0 >= 0) && (x0 < w);
        bool vx1 = (x0 + 1 >= 0) && (x0 + 1 < w);
        bool vy0 = (y0 >= 0) && (y0 < hh);
        bool vy1 = (y0 + 1 >= 0) && (y0 + 1 < hh);
        if (!(vx0 && vy0)) w00 = 0.f;
        if (!(vx1 && vy0)) w10 = 0.f;
        if (!(vx0 && vy1)) w01 = 0.f;
        if (!(vx1 && vy1)) w11 = 0.f;
        int cx0 = min(max(x0, 0), w - 1), cx1 = min(max(x0 + 1, 0), w - 1);
        int cy0 = min(max(y0, 0), hh - 1), cy1 = min(max(y0 + 1, 0), hh - 1);
        int rowbase = b * Tc + St[lvl];
        int slot = g * 136 + p * 8 + ((p >> 3) & 1) * 4;
        int4 wq4; wq4.x = __float_as_int(w00); wq4.y = __float_as_int(w10);
        wq4.z = __float_as_int(w01); wq4.w = __float_as_int(w11);
        int4 aq4;
        aq4.x = (rowbase + cy0 * w + cx0) * 512 + g * 64;
        aq4.y = (rowbase + cy0 * w + cx1) * 512 + g * 64;
        aq4.z = (rowbase + cy1 * w + cx0) * 512 + g * 64;
        aq4.w = (rowbase + cy1 * w + cx1) * 512 + g * 64;
        *(int4*)&pts[slot] = wq4;
        *(int4*)&pts[slot + 4] = aq4;
    }
    __syncthreads();

    const int group = t >> 5;               // head
    const int l32 = t & 31;
    const int d4 = (l32 & 15) * 4;
    const int ph = (l32 >> 4) * 8;
    const int xw = (l32 >> 4) * 4;
    const char* vbase = (const char*)value;
    float accL = 0.f, accH = 0.f;
    #pragma unroll
    for (int j = 0; j < 8; ++j) {
        int p = ph + j;
        int slot = group * 136 + p * 8 + xw;
        int4 wq = *(const int4*)&pts[slot];
        int4 aq = *(const int4*)&pts[slot + 4];
        unsigned u0 = *(const unsigned*)(vbase + (unsigned)(aq.x + d4));
        unsigned u1 = *(const unsigned*)(vbase + (unsigned)(aq.y + d4));
        unsigned u2 = *(const unsigned*)(vbase + (unsigned)(aq.z + d4));
        unsigned u3 = *(const unsigned*)(vbase + (unsigned)(aq.w + d4));
        float w00 = __int_as_float(wq.x), w10 = __int_as_float(wq.y);
        float w01 = __int_as_float(wq.z), w11 = __int_as_float(wq.w);
        // hi half: raw reinterpret (garbage low mantissa bits << bf16 rounding error)
        accL = fmaf(w00, bf_lo(u0), accL); accH = fmaf(w00, __int_as_float((int)u0), accH);
        accL = fmaf(w10, bf_lo(u1), accL); accH = fmaf(w10, __int_as_float((int)u1), accH);
        accL = fmaf(w01, bf_lo(u2), accL); accH = fmaf(w01, __int_as_float((int)u2), accH);
        accL = fmaf(w11, bf_lo(u3), accL); accH = fmaf(w11, __int_as_float((int)u3), accH);
    }
    accL += __shfl_xor(accL, 16);
    accH += __shfl_xor(accH, 16);
    if (l32 < 16) {
        unsigned pk = ((unsigned)(unsigned short)f2bf(accL)) |
                      (((unsigned)(unsigned short)f2bf(accH)) << 16);
        *(unsigned*)((char*)out + (size_t)bq * 512 + group * 64 + d4) = pk;
    }
}

extern "C" void kernel_launch(void* const* d_in, const int* in_sizes, int n_in,
                              void* d_out, int out_size, void* d_ws, size_t ws_size,
                              hipStream_t stream) {
    const float* src  = (const float*)d_in[0];
    const float* pos  = (const float*)d_in[1];
    const float* vr   = (const float*)d_in[2];
    const unsigned char* mask = (const unsigned char*)d_in[5];
    const float* Wv    = (const float*)d_in[6];
    const float* bv    = (const float*)d_in[7];
    const float* Woff  = (const float*)d_in[8];
    const float* boff  = (const float*)d_in[9];
    const float* Wattn = (const float*)d_in[10];
    const float* battn = (const float*)d_in[11];
    const float* Wout  = (const float*)d_in[12];
    const float* bout  = (const float*)d_in[13];
    const float* n1g   = (const float*)d_in[14];
    const float* n1b   = (const float*)d_in[15];
    const float* n2g   = (const float*)d_in[16];
    const float* n2b   = (const float*)d_in[17];
    const float* W1    = (const float*)d_in[18];
    const float* b1    = (const float*)d_in[19];
    const float* W2    = (const float*)d_in[20];
    const float* b2    = (const float*)d_in[21];
    float* out = (float*)d_out;

    const size_t R = (size_t)Bc * Tc;   // 26588

    // shorts/row: xb 256 | qb 256 | valb 256 | msdab 256 | oab 384 | srcb 256
    short* xb    = (short*)d_ws;
    short* qb    = xb + R * 256;
    short* valb  = qb + R * 256;
    short* msdab = valb + R * 256;
    short* oab   = msdab + R * 256;           // R*384
    short* srcb  = oab + R * 384;             // R*256 bf16 residual stream
    short* ln2b  = xb;                        // alias: xb dead by LN2 time
    short* hb    = qb;                        // alias: qb..oab >= R*1024, dead by ffn1
    short* wcT   = srcb + R * 256;            // 6*163840 ([640][256]: Wv|Woff|Wattn)
    short* woutT = wcT + 6 * 163840;          // 6*65536
    short* w1T   = woutT + 6 * 65536;         // 6*262144 ([1024][256])
    short* w2T   = w1T + 6 * 262144;          // 6*262144 ([256][1024])

    // one-time setup: all weight transposes in a single dispatch
    transpose_all<<<dim3(736, 1, 6), 256, 0, stream>>>(
        Wv, Woff, Wattn, Wout, W1, W2, wcT, woutT, w1T, w2T);

    const int M = (int)R;
    const int lnBlocks = (int)((R + 3) / 4);
    const int MT = (int)((R + 127) / 128);  // 208

    // layer 0 LN1 (fp32 src input)
    ln_kernel<<<lnBlocks, 256, 0, stream>>>(src, pos, n1g, n1b, xb, qb, M);

    for (int l = 0; l < NLAYERS; ++l) {
        // merged: [value | off | logits]; A = xb for cols<256, qb otherwise
        gemm_mfma<EPI_VALOA, 1, 0><<<dim3(MT, 10), 256, 0, stream>>>(
            xb, qb, wcT + (size_t)l * 163840, bv + l * Ec, boff + l * 256, battn + l * 128,
            nullptr, nullptr, mask, oab, valb, M, 640, 256);
        // MSDA (softmax fused) -> bf16
        msda_kernel<<<(int)R, 256, 0, stream>>>(valb, oab, vr, msdab);
        // src2 = cur + msda @ Wout + bout -> bf16 srcb
        if (l == 0)
            gemm_mfma<EPI_RES, 1, 0><<<dim3(MT, 4), 256, 0, stream>>>(
                msdab, nullptr, woutT + (size_t)l * 65536, bout + l * Ec, nullptr, nullptr,
                src, nullptr, nullptr, srcb, nullptr, M, 256, 256);
        else
            gemm_mfma<EPI_RES, 1, 1><<<dim3(MT, 4), 256, 0, stream>>>(
                msdab, nullptr, woutT + (size_t)l * 65536, bout + l * Ec, nullptr, nullptr,
                nullptr, srcb, nullptr, srcb, nullptr, M, 256, 256);
        // LN2 (bf16 in/out) -> ln2b
        ln_bf_kernel<<<lnBlocks, 256, 0, stream>>>(srcb, nullptr, n2g + l * Ec, n2b + l * Ec,
                                                   ln2b, nullptr, M);
        // h = relu(ln2 @ W1 + b1) -> bf16
        gemm_mfma<EPI_RELU, 1, 0><<<dim3(MT, 16), 256, 0, stream>>>(
            ln2b, nullptr, w1T + (size_t)l * 262144, b1 + l * FFNc, nullptr, nullptr,
            nullptr, nullptr, nullptr, hb, nullptr, M, 1024, 256);
        // src = src2 + h @ W2 + b2 ; last layer -> fp32 out, else bf16 srcb
        if (l < NLAYERS - 1) {
            gemm_mfma<EPI_RES, 1, 1><<<dim3(MT, 4), 256, 0, stream>>>(
                hb, nullptr, w2T + (size_t)l * 262144, b2 + l * Ec, nullptr, nullptr,
                nullptr, srcb, nullptr, srcb, nullptr, M, 256, 1024);
            // next-layer LN1 (+ q = x + pos, pos read fp32)
            ln_bf_kernel<<<lnBlocks, 256, 0, stream>>>(srcb, pos, n1g + (l + 1) * Ec,
                                                       n1b + (l + 1) * Ec, xb, qb, M);
        } else {
            gemm_mfma<EPI_RES, 0, 1><<<dim3(MT, 4), 256, 0, stream>>>(
                hb, nullptr, w2T + (size_t)l * 262144, b2 + l * Ec, nullptr, nullptr,
                nullptr, srcb, nullptr, out, nullptr, M, 256, 1024);
        }
    }
}

// Round 16
// 1034.752 us; speedup vs baseline: 1.1475x; 1.0218x over previous
//
#include <hip/hip_runtime.h>
#include <hip/hip_bf16.h>

#define NLAYERS 6
#define Bc 2
#define Tc 13294
#define Ec 256
#define NHc 8
#define FFNc 1024

#define EPI_BIAS 0
#define EPI_MASK 1
#define EPI_RES  2
#define EPI_RELU 3
#define EPI_VALOA 4

typedef __attribute__((ext_vector_type(8))) short bf16x8;
typedef __attribute__((ext_vector_type(4))) float f32x4;

typedef __attribute__((address_space(3))) unsigned int u32_lds;
typedef __attribute__((address_space(1))) unsigned int u32_glb;

__device__ __forceinline__ void gld16(const void* g, void* l) {
    __builtin_amdgcn_global_load_lds((const u32_glb*)g, (u32_lds*)l, 16, 0, 0);
}

__device__ __forceinline__ short f2bf(float f) {
    union { float f; unsigned u; } v; v.f = f;
    unsigned r = v.u + 0x7FFFu + ((v.u >> 16) & 1u);
    return (short)(r >> 16);
}
__device__ __forceinline__ float bf2f(short s) {
    union { unsigned u; float f; } v; v.u = ((unsigned)(unsigned short)s) << 16;
    return v.f;
}
__device__ __forceinline__ float bf_lo(unsigned u) {
    union { unsigned u; float f; } v; v.u = u << 16; return v.f;
}

// ---------------- LayerNorm fp32-in (+ q = x + pos), bf16 outputs; layer 0 only ----------------
__global__ __launch_bounds__(256) void ln_kernel(
    const float* __restrict__ src, const float* __restrict__ pos,
    const float* __restrict__ g, const float* __restrict__ b,
    short* __restrict__ x, short* __restrict__ q, int rows)
{
    int wave = threadIdx.x >> 6;
    int lane = threadIdx.x & 63;
    int row = blockIdx.x * 4 + wave;
    if (row >= rows) return;
    const float* p = src + (size_t)row * Ec;
    float4 v = *(const float4*)(p + lane * 4);
    float s  = v.x + v.y + v.z + v.w;
    float sq = v.x*v.x + v.y*v.y + v.z*v.z + v.w*v.w;
    #pragma unroll
    for (int o = 32; o; o >>= 1) { s += __shfl_xor(s, o); sq += __shfl_xor(sq, o); }
    float mean = s * (1.f / Ec);
    float var  = sq * (1.f / Ec) - mean * mean;
    float inv  = rsqrtf(var + 1e-5f);
    float4 gg = *(const float4*)(g + lane * 4);
    float4 bb = *(const float4*)(b + lane * 4);
    float xo0 = (v.x - mean) * inv * gg.x + bb.x;
    float xo1 = (v.y - mean) * inv * gg.y + bb.y;
    float xo2 = (v.z - mean) * inv * gg.z + bb.z;
    float xo3 = (v.w - mean) * inv * gg.w + bb.w;
    short4 xs; xs.x = f2bf(xo0); xs.y = f2bf(xo1); xs.z = f2bf(xo2); xs.w = f2bf(xo3);
    *(short4*)(x + (size_t)row * Ec + lane * 4) = xs;
    float4 pp = *(const float4*)(pos + (size_t)row * Ec + lane * 4);
    short4 qs;
    qs.x = f2bf(xo0 + pp.x); qs.y = f2bf(xo1 + pp.y);
    qs.z = f2bf(xo2 + pp.z); qs.w = f2bf(xo3 + pp.w);
    *(short4*)(q + (size_t)row * Ec + lane * 4) = qs;
}

// ---------------- LayerNorm bf16-in, bf16 out (+ optional q = x + pos_fp32) ----------------
__global__ __launch_bounds__(256) void ln_bf_kernel(
    const short* __restrict__ src, const float* __restrict__ pos,
    const float* __restrict__ g, const float* __restrict__ b,
    short* __restrict__ x, short* __restrict__ q, int rows)
{
    int wave = threadIdx.x >> 6;
    int lane = threadIdx.x & 63;
    int row = blockIdx.x * 4 + wave;
    if (row >= rows) return;
    short4 v4 = *(const short4*)(src + (size_t)row * Ec + lane * 4);
    float v0 = bf2f(v4.x), v1 = bf2f(v4.y), v2 = bf2f(v4.z), v3 = bf2f(v4.w);
    float s  = v0 + v1 + v2 + v3;
    float sq = v0*v0 + v1*v1 + v2*v2 + v3*v3;
    #pragma unroll
    for (int o = 32; o; o >>= 1) { s += __shfl_xor(s, o); sq += __shfl_xor(sq, o); }
    float mean = s * (1.f / Ec);
    float var  = sq * (1.f / Ec) - mean * mean;
    float inv  = rsqrtf(var + 1e-5f);
    float4 gg = *(const float4*)(g + lane * 4);
    float4 bb = *(const float4*)(b + lane * 4);
    float xo0 = (v0 - mean) * inv * gg.x + bb.x;
    float xo1 = (v1 - mean) * inv * gg.y + bb.y;
    float xo2 = (v2 - mean) * inv * gg.z + bb.z;
    float xo3 = (v3 - mean) * inv * gg.w + bb.w;
    short4 xs; xs.x = f2bf(xo0); xs.y = f2bf(xo1); xs.z = f2bf(xo2); xs.w = f2bf(xo3);
    *(short4*)(x + (size_t)row * Ec + lane * 4) = xs;
    if (q) {
        float4 pp = *(const float4*)(pos + (size_t)row * Ec + lane * 4);
        short4 qs;
        qs.x = f2bf(xo0 + pp.x); qs.y = f2bf(xo1 + pp.y);
        qs.z = f2bf(xo2 + pp.z); qs.w = f2bf(xo3 + pp.w);
        *(short4*)(q + (size_t)row * Ec + lane * 4) = qs;
    }
}

// ---------------- merged weight transpose+convert: all 6 weights in one dispatch ----------------
__global__ __launch_bounds__(256) void transpose_all(
    const float* __restrict__ Wv,   const float* __restrict__ Woff,
    const float* __restrict__ Wattn,const float* __restrict__ Wout,
    const float* __restrict__ W1,   const float* __restrict__ W2,
    short* __restrict__ wcT, short* __restrict__ woutT,
    short* __restrict__ w1T, short* __restrict__ w2T)
{
    __shared__ float tile[32][33];
    const int l = blockIdx.z;
    const int t = blockIdx.x;
    const float* W; short* Wt; int K, N, lstr, rowOff, n0, k0;
    if (t < 64)       { W = Wv;    Wt = wcT;   K = 256;  N = 256;  lstr = 163840; rowOff = 0;
                        int u = t;        n0 = (u & 7) * 32;  k0 = (u >> 3) * 32; }
    else if (t < 128) { W = Woff;  Wt = wcT;   K = 256;  N = 256;  lstr = 163840; rowOff = 256;
                        int u = t - 64;   n0 = (u & 7) * 32;  k0 = (u >> 3) * 32; }
    else if (t < 160) { W = Wattn; Wt = wcT;   K = 256;  N = 128;  lstr = 163840; rowOff = 512;
                        int u = t - 128;  n0 = (u & 3) * 32;  k0 = (u >> 2) * 32; }
    else if (t < 224) { W = Wout;  Wt = woutT; K = 256;  N = 256;  lstr = 65536;  rowOff = 0;
                        int u = t - 160;  n0 = (u & 7) * 32;  k0 = (u >> 3) * 32; }
    else if (t < 480) { W = W1;    Wt = w1T;   K = 256;  N = 1024; lstr = 262144; rowOff = 0;
                        int u = t - 224;  n0 = (u & 31) * 32; k0 = (u >> 5) * 32; }
    else              { W = W2;    Wt = w2T;   K = 1024; N = 256;  lstr = 262144; rowOff = 0;
                        int u = t - 480;  n0 = (u & 7) * 32;  k0 = (u >> 3) * 32; }
    const float* Wl = W + (size_t)l * K * N;
    short* Wtl = Wt + (size_t)l * lstr;
    int tx = threadIdx.x & 31, ty = threadIdx.x >> 5;
    #pragma unroll
    for (int i = 0; i < 32; i += 8)
        tile[ty + i][tx] = Wl[(size_t)(k0 + ty + i) * N + n0 + tx];
    __syncthreads();
    #pragma unroll
    for (int i = 0; i < 32; i += 8)
        Wtl[(size_t)(rowOff + n0 + ty + i) * K + k0 + tx] = f2bf(tile[tx][ty + i]);
}

// ---------------- bf16 MFMA GEMM: 128x64 tile, BK=32, double-buffered LDS ----------------
// R15 structure (measured best): swapped MFMA operands -> C^T fragments; per lane the M-row
// is fixed (lane&15) and each (mi,ni) holds 4 CONSECUTIVE N-cols -> packed short4/float4
// epilogue stores + vector bias/residual loads.
template<int EPI, int OBF, int RESBF>
__global__ __launch_bounds__(256) void gemm_mfma(
    const short* __restrict__ A, const short* __restrict__ A2,
    const short* __restrict__ Bt,
    const float* __restrict__ bias, const float* __restrict__ bias2,
    const float* __restrict__ bias3,
    const float* __restrict__ resf, const short* __restrict__ resb,
    const unsigned char* __restrict__ mask,
    void* __restrict__ Cout, void* __restrict__ Cout2, int M, int N, int K)
{
    __shared__ short As[2][128 * 32];
    __shared__ short Bs[2][64 * 32];
    const int tid = threadIdx.x;
    const int lane = tid & 63;
    const int wv = tid >> 6;
    const int row0 = blockIdx.x * 128;
    const int col0 = blockIdx.y * 64;
    const int mbase = (wv >> 1) * 64;   // wave tile: 64 rows x 32 cols
    const int nbase = (wv & 1) * 32;
    const int lr = lane & 15;
    const int kg = lane >> 4;

    const short* Ause = (EPI == EPI_VALOA && blockIdx.y >= 4) ? A2 : A;

    f32x4 zf = {0.f, 0.f, 0.f, 0.f};
    f32x4 acc[4][2];
    #pragma unroll
    for (int i = 0; i < 4; ++i)
        #pragma unroll
        for (int j = 0; j < 2; ++j) acc[i][j] = zf;

    const int scol = (lane & 3) * 8;
    const int srowA = wv * 32 + (lane >> 2);
    const short* Ap = Ause + (size_t)(row0 + srowA) * K + scol;
    const int lA0 = srowA * 32 + scol;
    const int lA1 = lA0 + 16 * 32;
    const int srowB = wv * 16 + (lane >> 2);
    const short* Bp = Bt + (size_t)(col0 + srowB) * K + scol;
    const int lB = srowB * 32 + scol;

    #define STAGE(buf, k0) do { \
        gld16(Ap + (k0),                &As[buf][lA0]); \
        gld16(Ap + (size_t)16*K + (k0), &As[buf][lA1]); \
        gld16(Bp + (k0),                &Bs[buf][lB]); \
    } while (0)

    STAGE(0, 0);
    __syncthreads();
    int cur = 0;
    for (int k0 = 0; k0 < K; k0 += 32) {
        if (k0 + 32 < K) STAGE(cur ^ 1, k0 + 32);
        bf16x8 af[4], bfr[2];
        #pragma unroll
        for (int i = 0; i < 4; ++i)
            af[i]  = *(const bf16x8*)&As[cur][(mbase + i * 16 + lr) * 32 + kg * 8];
        #pragma unroll
        for (int j = 0; j < 2; ++j)
            bfr[j] = *(const bf16x8*)&Bs[cur][(nbase + j * 16 + lr) * 32 + kg * 8];
        // operand swap: D = B^T-fragment x A-fragment -> C^T lane layout
        #pragma unroll
        for (int mi = 0; mi < 4; ++mi)
            #pragma unroll
            for (int ni = 0; ni < 2; ++ni)
                acc[mi][ni] = __builtin_amdgcn_mfma_f32_16x16x32_bf16(
                    bfr[ni], af[mi], acc[mi][ni], 0, 0, 0);
        __syncthreads();
        cur ^= 1;
    }
    #undef STAGE

    // epilogue: per lane, row = row0+mbase+mi*16+lr; cols = col0+nbase+ni*16+kg*4 .. +3
    float* Cf = (float*)Cout;
    short* Cb = (short*)Cout;
    short* Vb = (short*)Cout2;
    #pragma unroll
    for (int ni = 0; ni < 2; ++ni) {
        const int colb = col0 + nbase + ni * 16 + kg * 4;   // 4 consecutive cols
        float4 bz4;
        if (EPI == EPI_VALOA) {
            const float* bp = (colb < 256) ? (bias + colb)
                             : ((colb < 512) ? (bias2 + colb - 256) : (bias3 + colb - 512));
            bz4 = *(const float4*)bp;
        } else {
            bz4 = *(const float4*)(bias + colb);
        }
        #pragma unroll
        for (int mi = 0; mi < 4; ++mi) {
            int grow = row0 + mbase + mi * 16 + lr;
            if (grow >= M) continue;
            float v0 = acc[mi][ni][0] + bz4.x;
            float v1 = acc[mi][ni][1] + bz4.y;
            float v2 = acc[mi][ni][2] + bz4.z;
            float v3 = acc[mi][ni][3] + bz4.w;
            if (EPI == EPI_VALOA) {
                if (colb < 256) {
                    if (mask[grow]) { v0 = 0.f; v1 = 0.f; v2 = 0.f; v3 = 0.f; }
                    short4 s; s.x = f2bf(v0); s.y = f2bf(v1); s.z = f2bf(v2); s.w = f2bf(v3);
                    *(short4*)(Vb + (size_t)grow * 256 + colb) = s;
                } else {
                    short4 s; s.x = f2bf(v0); s.y = f2bf(v1); s.z = f2bf(v2); s.w = f2bf(v3);
                    *(short4*)(Cb + (size_t)grow * 384 + (colb - 256)) = s;
                }
                continue;
            }
            if (EPI == EPI_RES) {
                if (RESBF) {
                    short4 r = *(const short4*)(resb + (size_t)grow * N + colb);
                    v0 += bf2f(r.x); v1 += bf2f(r.y); v2 += bf2f(r.z); v3 += bf2f(r.w);
                } else {
                    float4 r = *(const float4*)(resf + (size_t)grow * N + colb);
                    v0 += r.x; v1 += r.y; v2 += r.z; v3 += r.w;
                }
            }
            if (EPI == EPI_RELU) {
                v0 = v0 > 0.f ? v0 : 0.f; v1 = v1 > 0.f ? v1 : 0.f;
                v2 = v2 > 0.f ? v2 : 0.f; v3 = v3 > 0.f ? v3 : 0.f;
            }
            if (OBF) {
                short4 s; s.x = f2bf(v0); s.y = f2bf(v1); s.z = f2bf(v2); s.w = f2bf(v3);
                *(short4*)(Cb + (size_t)grow * N + colb) = s;
            } else {
                float4 s; s.x = v0; s.y = v1; s.z = v2; s.w = v3;
                *(float4*)(Cf + (size_t)grow * N + colb) = s;
            }
        }
    }
}

// ---------------- MSDA with fused softmax; value + oa bf16 ----------------
// NEW: XCD-chunk swizzle of blockIdx -> bq (bijective m204 variant): each XCD's private L2
// serves a contiguous spatial band of queries -> higher L2 hit rate on the gathered value
// lines (was 6.4x HBM over-fetch). Pure index permutation, correctness unconditional.
// block = one bq (all 8 heads); phase-1 compacted onto threads 0..127;
// phase-2: 32-lane group per head; lane owns 2 dims (dword, 16 lanes/64B row).
__global__ __launch_bounds__(256) void msda_kernel(
    const short* __restrict__ value, const short* __restrict__ oa,
    const float* __restrict__ vr, short* __restrict__ out)
{
    __shared__ int pts[8 * 136];
    const int t = threadIdx.x;
    // bijective XCD-chunk swizzle: nwg = 2*Tc = 26588; q = 3323, r = 4
    const int nwgq = (2 * Tc) >> 3;          // 3323
    const int nwgr = (2 * Tc) & 7;           // 4
    const int xcd = blockIdx.x & 7;
    const int idx = blockIdx.x >> 3;
    const int bq = (xcd < nwgr ? xcd * (nwgq + 1)
                               : nwgr * (nwgq + 1) + (xcd - nwgr) * nwgq) + idx;
    const int b = (bq >= Tc) ? 1 : 0;
    const int qq = bq - b * Tc;

    if (t < 128) {
        const int g = t >> 4;        // group == head
        const int p = t & 15;
        const int lvl = p >> 2;
        const int St[4] = {0, 10000, 12500, 13125};
        int qi, Wq, qlvl;
        if (qq < 10000)      { qlvl = 0; qi = qq;         Wq = 100; }
        else if (qq < 12500) { qlvl = 1; qi = qq - 10000; Wq = 50; }
        else if (qq < 13125) { qlvl = 2; qi = qq - 12500; Wq = 25; }
        else                 { qlvl = 3; qi = qq - 13125; Wq = 13; }
        float base_x = (0.5f + (float)(qi % Wq)) / (vr[(b*4+qlvl)*2+0] * (float)Wq);
        float base_y = (0.5f + (float)(qi / Wq)) / (vr[(b*4+qlvl)*2+1] * (float)Wq);

        // softmax over 16 logits (one per lane; 16-lane group is wave-aligned)
        float logit = bf2f(oa[(size_t)bq * 384 + 256 + g * 16 + p]);
        float mx = logit;
        #pragma unroll
        for (int o = 8; o; o >>= 1) mx = fmaxf(mx, __shfl_xor(mx, o));
        float e = __expf(logit - mx);
        float sum = e;
        #pragma unroll
        for (int o = 8; o; o >>= 1) sum += __shfl_xor(sum, o);
        float aw = e * __frcp_rn(sum);

        const int w = (lvl == 0) ? 100 : ((lvl == 1) ? 50 : ((lvl == 2) ? 25 : 13));
        const int hh = w;
        const float wf = (float)w;
        const float refxw = base_x * vr[(b*4+lvl)*2+0] * wf;
        const float refyw = base_y * vr[(b*4+lvl)*2+1] * wf;
        const float ox = bf2f(oa[(size_t)bq * 384 + g * 32 + p * 2 + 0]);
        const float oy = bf2f(oa[(size_t)bq * 384 + g * 32 + p * 2 + 1]);
        float xf = refxw + ox - 0.5f;
        float yf = refyw + oy - 0.5f;
        float x0f = floorf(xf), y0f = floorf(yf);
        int x0 = (int)x0f, y0 = (int)y0f;
        float wx = xf - x0f, wy = yf - y0f;
        float w00 = (1.f - wx) * (1.f - wy) * aw;
        float w10 = wx * (1.f - wy) * aw;
        float w01 = (1.f - wx) * wy * aw;
        float w11 = wx * wy * aw;
        bool vx0 = (x0 >= 0) && (x0 < w);
        bool vx1 = (x0 + 1 >= 0) && (x0 + 1 < w);
        bool vy0 = (y0 >= 0) && (y0 < hh);
        bool vy1 = (y0 + 1 >= 0) && (y0 + 1 < hh);
        if (!(vx0 && vy0)) w00 = 0.f;
        if (!(vx1 && vy0)) w10 = 0.f;
        if (!(vx0 && vy1)) w01 = 0.f;
        if (!(vx1 && vy1)) w11 = 0.f;
        int cx0 = min(max(x0, 0), w - 1), cx1 = min(max(x0 + 1, 0), w - 1);
        int cy0 = min(max(y0, 0), hh - 1), cy1 = min(max(y0 + 1, 0), hh - 1);
        int rowbase = b * Tc + St[lvl];
        int slot = g * 136 + p * 8 + ((p >> 3) & 1) * 4;
        int4 wq4; wq4.x = __float_as_int(w00); wq4.y = __float_as_int(w10);
        wq4.z = __float_as_int(w01); wq4.w = __float_as_int(w11);
        int4 aq4;
        aq4.x = (rowbase + cy0 * w + cx0) * 512 + g * 64;
        aq4.y = (rowbase + cy0 * w + cx1) * 512 + g * 64;
        aq4.z = (rowbase + cy1 * w + cx0) * 512 + g * 64;
        aq4.w = (rowbase + cy1 * w + cx1) * 512 + g * 64;
        *(int4*)&pts[slot] = wq4;
        *(int4*)&pts[slot + 4] = aq4;
    }
    __syncthreads();

    const int group = t >> 5;               // head
    const int l32 = t & 31;
    const int d4 = (l32 & 15) * 4;
    const int ph = (l32 >> 4) * 8;
    const int xw = (l32 >> 4) * 4;
    const char* vbase = (const char*)value;
    float accL = 0.f, accH = 0.f;
    #pragma unroll
    for (int j = 0; j < 8; ++j) {
        int p = ph + j;
        int slot = group * 136 + p * 8 + xw;
        int4 wq = *(const int4*)&pts[slot];
        int4 aq = *(const int4*)&pts[slot + 4];
        unsigned u0 = *(const unsigned*)(vbase + (unsigned)(aq.x + d4));
        unsigned u1 = *(const unsigned*)(vbase + (unsigned)(aq.y + d4));
        unsigned u2 = *(const unsigned*)(vbase + (unsigned)(aq.z + d4));
        unsigned u3 = *(const unsigned*)(vbase + (unsigned)(aq.w + d4));
        float w00 = __int_as_float(wq.x), w10 = __int_as_float(wq.y);
        float w01 = __int_as_float(wq.z), w11 = __int_as_float(wq.w);
        // hi half: raw reinterpret (garbage low mantissa bits << bf16 rounding error)
        accL = fmaf(w00, bf_lo(u0), accL); accH = fmaf(w00, __int_as_float((int)u0), accH);
        accL = fmaf(w10, bf_lo(u1), accL); accH = fmaf(w10, __int_as_float((int)u1), accH);
        accL = fmaf(w01, bf_lo(u2), accL); accH = fmaf(w01, __int_as_float((int)u2), accH);
        accL = fmaf(w11, bf_lo(u3), accL); accH = fmaf(w11, __int_as_float((int)u3), accH);
    }
    accL += __shfl_xor(accL, 16);
    accH += __shfl_xor(accH, 16);
    if (l32 < 16) {
        unsigned pk = ((unsigned)(unsigned short)f2bf(accL)) |
                      (((unsigned)(unsigned short)f2bf(accH)) << 16);
        *(unsigned*)((char*)out + (size_t)bq * 512 + group * 64 + d4) = pk;
    }
}

extern "C" void kernel_launch(void* const* d_in, const int* in_sizes, int n_in,
                              void* d_out, int out_size, void* d_ws, size_t ws_size,
                              hipStream_t stream) {
    const float* src  = (const float*)d_in[0];
    const float* pos  = (const float*)d_in[1];
    const float* vr   = (const float*)d_in[2];
    const unsigned char* mask = (const unsigned char*)d_in[5];
    const float* Wv    = (const float*)d_in[6];
    const float* bv    = (const float*)d_in[7];
    const float* Woff  = (const float*)d_in[8];
    const float* boff  = (const float*)d_in[9];
    const float* Wattn = (const float*)d_in[10];
    const float* battn = (const float*)d_in[11];
    const float* Wout  = (const float*)d_in[12];
    const float* bout  = (const float*)d_in[13];
    const float* n1g   = (const float*)d_in[14];
    const float* n1b   = (const float*)d_in[15];
    const float* n2g   = (const float*)d_in[16];
    const float* n2b   = (const float*)d_in[17];
    const float* W1    = (const float*)d_in[18];
    const float* b1    = (const float*)d_in[19];
    const float* W2    = (const float*)d_in[20];
    const float* b2    = (const float*)d_in[21];
    float* out = (float*)d_out;

    const size_t R = (size_t)Bc * Tc;   // 26588

    // shorts/row: xb 256 | qb 256 | valb 256 | msdab 256 | oab 384 | srcb 256
    short* xb    = (short*)d_ws;
    short* qb    = xb + R * 256;
    short* valb  = qb + R * 256;
    short* msdab = valb + R * 256;
    short* oab   = msdab + R * 256;           // R*384
    short* srcb  = oab + R * 384;             // R*256 bf16 residual stream
    short* ln2b  = xb;                        // alias: xb dead by LN2 time
    short* hb    = qb;                        // alias: qb..oab >= R*1024, dead by ffn1
    short* wcT   = srcb + R * 256;            // 6*163840 ([640][256]: Wv|Woff|Wattn)
    short* woutT = wcT + 6 * 163840;          // 6*65536
    short* w1T   = woutT + 6 * 65536;         // 6*262144 ([1024][256])
    short* w2T   = w1T + 6 * 262144;          // 6*262144 ([256][1024])

    // one-time setup: all weight transposes in a single dispatch
    transpose_all<<<dim3(736, 1, 6), 256, 0, stream>>>(
        Wv, Woff, Wattn, Wout, W1, W2, wcT, woutT, w1T, w2T);

    const int M = (int)R;
    const int lnBlocks = (int)((R + 3) / 4);
    const int MT = (int)((R + 127) / 128);  // 208

    // layer 0 LN1 (fp32 src input)
    ln_kernel<<<lnBlocks, 256, 0, stream>>>(src, pos, n1g, n1b, xb, qb, M);

    for (int l = 0; l < NLAYERS; ++l) {
        // merged: [value | off | logits]; A = xb for cols<256, qb otherwise
        gemm_mfma<EPI_VALOA, 1, 0><<<dim3(MT, 10), 256, 0, stream>>>(
            xb, qb, wcT + (size_t)l * 163840, bv + l * Ec, boff + l * 256, battn + l * 128,
            nullptr, nullptr, mask, oab, valb, M, 640, 256);
        // MSDA (softmax fused) -> bf16
        msda_kernel<<<(int)R, 256, 0, stream>>>(valb, oab, vr, msdab);
        // src2 = cur + msda @ Wout + bout -> bf16 srcb
        if (l == 0)
            gemm_mfma<EPI_RES, 1, 0><<<dim3(MT, 4), 256, 0, stream>>>(
                msdab, nullptr, woutT + (size_t)l * 65536, bout + l * Ec, nullptr, nullptr,
                src, nullptr, nullptr, srcb, nullptr, M, 256, 256);
        else
            gemm_mfma<EPI_RES, 1, 1><<<dim3(MT, 4), 256, 0, stream>>>(
                msdab, nullptr, woutT + (size_t)l * 65536, bout + l * Ec, nullptr, nullptr,
                nullptr, srcb, nullptr, srcb, nullptr, M, 256, 256);
        // LN2 (bf16 in/out) -> ln2b
        ln_bf_kernel<<<lnBlocks, 256, 0, stream>>>(srcb, nullptr, n2g + l * Ec, n2b + l * Ec,
                                                   ln2b, nullptr, M);
        // h = relu(ln2 @ W1 + b1) -> bf16
        gemm_mfma<EPI_RELU, 1, 0><<<dim3(MT, 16), 256, 0, stream>>>(
            ln2b, nullptr, w1T + (size_t)l * 262144, b1 + l * FFNc, nullptr, nullptr,
            nullptr, nullptr, nullptr, hb, nullptr, M, 1024, 256);
        // src = src2 + h @ W2 + b2 ; last layer -> fp32 out, else bf16 srcb
        if (l < NLAYERS - 1) {
            gemm_mfma<EPI_RES, 1, 1><<<dim3(MT, 4), 256, 0, stream>>>(
                hb, nullptr, w2T + (size_t)l * 262144, b2 + l * Ec, nullptr, nullptr,
                nullptr, srcb, nullptr, srcb, nullptr, M, 256, 1024);
            // next-layer LN1 (+ q = x + pos, pos read fp32)
            ln_bf_kernel<<<lnBlocks, 256, 0, stream>>>(srcb, pos, n1g + (l + 1) * Ec,
                                                       n1b + (l + 1) * Ec, xb, qb, M);
        } else {
            gemm_mfma<EPI_RES, 0, 1><<<dim3(MT, 4), 256, 0, stream>>>(
                hb, nullptr, w2T + (size_t)l * 262144, b2 + l * Ec, nullptr, nullptr,
                nullptr, srcb, nullptr, out, nullptr, M, 256, 1024);
        }
    }
}

// Round 17
// 1027.698 us; speedup vs baseline: 1.1553x; 1.0069x over previous
//
#include <hip/hip_runtime.h>
#include <hip/hip_bf16.h>

#define NLAYERS 6
#define Bc 2
#define Tc 13294
#define Ec 256
#define NHc 8
#define FFNc 1024

#define EPI_BIAS 0
#define EPI_MASK 1
#define EPI_RES  2
#define EPI_RELU 3
#define EPI_VALOA 4

typedef __attribute__((ext_vector_type(8))) short bf16x8;
typedef __attribute__((ext_vector_type(4))) float f32x4;

typedef __attribute__((address_space(3))) unsigned int u32_lds;
typedef __attribute__((address_space(1))) unsigned int u32_glb;

__device__ __forceinline__ void gld16(const void* g, void* l) {
    __builtin_amdgcn_global_load_lds((const u32_glb*)g, (u32_lds*)l, 16, 0, 0);
}

__device__ __forceinline__ short f2bf(float f) {
    union { float f; unsigned u; } v; v.f = f;
    unsigned r = v.u + 0x7FFFu + ((v.u >> 16) & 1u);
    return (short)(r >> 16);
}
__device__ __forceinline__ float bf2f(short s) {
    union { unsigned u; float f; } v; v.u = ((unsigned)(unsigned short)s) << 16;
    return v.f;
}
__device__ __forceinline__ float bf_lo(unsigned u) {
    union { unsigned u; float f; } v; v.u = u << 16; return v.f;
}

// ---------------- LayerNorm fp32-in (+ q = x + pos), bf16 outputs; layer 0 only ----------------
__global__ __launch_bounds__(256) void ln_kernel(
    const float* __restrict__ src, const float* __restrict__ pos,
    const float* __restrict__ g, const float* __restrict__ b,
    short* __restrict__ x, short* __restrict__ q, int rows)
{
    int wave = threadIdx.x >> 6;
    int lane = threadIdx.x & 63;
    int row = blockIdx.x * 4 + wave;
    if (row >= rows) return;
    const float* p = src + (size_t)row * Ec;
    float4 v = *(const float4*)(p + lane * 4);
    float s  = v.x + v.y + v.z + v.w;
    float sq = v.x*v.x + v.y*v.y + v.z*v.z + v.w*v.w;
    #pragma unroll
    for (int o = 32; o; o >>= 1) { s += __shfl_xor(s, o); sq += __shfl_xor(sq, o); }
    float mean = s * (1.f / Ec);
    float var  = sq * (1.f / Ec) - mean * mean;
    float inv  = rsqrtf(var + 1e-5f);
    float4 gg = *(const float4*)(g + lane * 4);
    float4 bb = *(const float4*)(b + lane * 4);
    float xo0 = (v.x - mean) * inv * gg.x + bb.x;
    float xo1 = (v.y - mean) * inv * gg.y + bb.y;
    float xo2 = (v.z - mean) * inv * gg.z + bb.z;
    float xo3 = (v.w - mean) * inv * gg.w + bb.w;
    short4 xs; xs.x = f2bf(xo0); xs.y = f2bf(xo1); xs.z = f2bf(xo2); xs.w = f2bf(xo3);
    *(short4*)(x + (size_t)row * Ec + lane * 4) = xs;
    float4 pp = *(const float4*)(pos + (size_t)row * Ec + lane * 4);
    short4 qs;
    qs.x = f2bf(xo0 + pp.x); qs.y = f2bf(xo1 + pp.y);
    qs.z = f2bf(xo2 + pp.z); qs.w = f2bf(xo3 + pp.w);
    *(short4*)(q + (size_t)row * Ec + lane * 4) = qs;
}

// ---------------- LayerNorm bf16-in, bf16 out (+ optional q = x + pos_fp32) ----------------
__global__ __launch_bounds__(256) void ln_bf_kernel(
    const short* __restrict__ src, const float* __restrict__ pos,
    const float* __restrict__ g, const float* __restrict__ b,
    short* __restrict__ x, short* __restrict__ q, int rows)
{
    int wave = threadIdx.x >> 6;
    int lane = threadIdx.x & 63;
    int row = blockIdx.x * 4 + wave;
    if (row >= rows) return;
    short4 v4 = *(const short4*)(src + (size_t)row * Ec + lane * 4);
    float v0 = bf2f(v4.x), v1 = bf2f(v4.y), v2 = bf2f(v4.z), v3 = bf2f(v4.w);
    float s  = v0 + v1 + v2 + v3;
    float sq = v0*v0 + v1*v1 + v2*v2 + v3*v3;
    #pragma unroll
    for (int o = 32; o; o >>= 1) { s += __shfl_xor(s, o); sq += __shfl_xor(sq, o); }
    float mean = s * (1.f / Ec);
    float var  = sq * (1.f / Ec) - mean * mean;
    float inv  = rsqrtf(var + 1e-5f);
    float4 gg = *(const float4*)(g + lane * 4);
    float4 bb = *(const float4*)(b + lane * 4);
    float xo0 = (v0 - mean) * inv * gg.x + bb.x;
    float xo1 = (v1 - mean) * inv * gg.y + bb.y;
    float xo2 = (v2 - mean) * inv * gg.z + bb.z;
    float xo3 = (v3 - mean) * inv * gg.w + bb.w;
    short4 xs; xs.x = f2bf(xo0); xs.y = f2bf(xo1); xs.z = f2bf(xo2); xs.w = f2bf(xo3);
    *(short4*)(x + (size_t)row * Ec + lane * 4) = xs;
    if (q) {
        float4 pp = *(const float4*)(pos + (size_t)row * Ec + lane * 4);
        short4 qs;
        qs.x = f2bf(xo0 + pp.x); qs.y = f2bf(xo1 + pp.y);
        qs.z = f2bf(xo2 + pp.z); qs.w = f2bf(xo3 + pp.w);
        *(short4*)(q + (size_t)row * Ec + lane * 4) = qs;
    }
}

// ---------------- merged weight transpose+convert: all 6 weights in one dispatch ----------------
__global__ __launch_bounds__(256) void transpose_all(
    const float* __restrict__ Wv,   const float* __restrict__ Woff,
    const float* __restrict__ Wattn,const float* __restrict__ Wout,
    const float* __restrict__ W1,   const float* __restrict__ W2,
    short* __restrict__ wcT, short* __restrict__ woutT,
    short* __restrict__ w1T, short* __restrict__ w2T)
{
    __shared__ float tile[32][33];
    const int l = blockIdx.z;
    const int t = blockIdx.x;
    const float* W; short* Wt; int K, N, lstr, rowOff, n0, k0;
    if (t < 64)       { W = Wv;    Wt = wcT;   K = 256;  N = 256;  lstr = 163840; rowOff = 0;
                        int u = t;        n0 = (u & 7) * 32;  k0 = (u >> 3) * 32; }
    else if (t < 128) { W = Woff;  Wt = wcT;   K = 256;  N = 256;  lstr = 163840; rowOff = 256;
                        int u = t - 64;   n0 = (u & 7) * 32;  k0 = (u >> 3) * 32; }
    else if (t < 160) { W = Wattn; Wt = wcT;   K = 256;  N = 128;  lstr = 163840; rowOff = 512;
                        int u = t - 128;  n0 = (u & 3) * 32;  k0 = (u >> 2) * 32; }
    else if (t < 224) { W = Wout;  Wt = woutT; K = 256;  N = 256;  lstr = 65536;  rowOff = 0;
                        int u = t - 160;  n0 = (u & 7) * 32;  k0 = (u >> 3) * 32; }
    else if (t < 480) { W = W1;    Wt = w1T;   K = 256;  N = 1024; lstr = 262144; rowOff = 0;
                        int u = t - 224;  n0 = (u & 31) * 32; k0 = (u >> 5) * 32; }
    else              { W = W2;    Wt = w2T;   K = 1024; N = 256;  lstr = 262144; rowOff = 0;
                        int u = t - 480;  n0 = (u & 7) * 32;  k0 = (u >> 3) * 32; }
    const float* Wl = W + (size_t)l * K * N;
    short* Wtl = Wt + (size_t)l * lstr;
    int tx = threadIdx.x & 31, ty = threadIdx.x >> 5;
    #pragma unroll
    for (int i = 0; i < 32; i += 8)
        tile[ty + i][tx] = Wl[(size_t)(k0 + ty + i) * N + n0 + tx];
    __syncthreads();
    #pragma unroll
    for (int i = 0; i < 32; i += 8)
        Wtl[(size_t)(rowOff + n0 + ty + i) * K + k0 + tx] = f2bf(tile[tx][ty + i]);
}

// ---------------- bf16 MFMA GEMM: 128x64 tile, BK=32, double-buffered LDS ----------------
// R15 compute structure (swapped-operand C^T fragments, packed epilogue).
// NEW: 1D grid + bijective XCD-chunk swizzle, row-major linearization: each XCD owns a
// contiguous band of ~26 row-tiles x ALL col-tiles -> its A working set (~1.7MB) is
// L2-resident, so per-col-tile A re-reads become L2 hits instead of LLC round-trips.
// Grid size = MT*NT, MT=208 divisible by 8 -> chunk map is exact (r=0).
template<int EPI, int OBF, int RESBF>
__global__ __launch_bounds__(256) void gemm_mfma(
    const short* __restrict__ A, const short* __restrict__ A2,
    const short* __restrict__ Bt,
    const float* __restrict__ bias, const float* __restrict__ bias2,
    const float* __restrict__ bias3,
    const float* __restrict__ resf, const short* __restrict__ resb,
    const unsigned char* __restrict__ mask,
    void* __restrict__ Cout, void* __restrict__ Cout2, int M, int N, int K)
{
    __shared__ short As[2][128 * 32];
    __shared__ short Bs[2][64 * 32];
    const int tid = threadIdx.x;
    const int lane = tid & 63;
    const int wv = tid >> 6;
    // XCD-chunk swizzle (bijective; gridDim.x % 8 == 0)
    const int nt = N >> 6;
    const int qc = gridDim.x >> 3;
    const int lin = (blockIdx.x & 7) * qc + (blockIdx.x >> 3);
    const int rowTile = lin / nt;
    const int colTile = lin - rowTile * nt;
    const int row0 = rowTile * 128;
    const int col0 = colTile * 64;
    const int mbase = (wv >> 1) * 64;   // wave tile: 64 rows x 32 cols
    const int nbase = (wv & 1) * 32;
    const int lr = lane & 15;
    const int kg = lane >> 4;

    const short* Ause = (EPI == EPI_VALOA && colTile >= 4) ? A2 : A;

    f32x4 zf = {0.f, 0.f, 0.f, 0.f};
    f32x4 acc[4][2];
    #pragma unroll
    for (int i = 0; i < 4; ++i)
        #pragma unroll
        for (int j = 0; j < 2; ++j) acc[i][j] = zf;

    const int scol = (lane & 3) * 8;
    const int srowA = wv * 32 + (lane >> 2);
    const short* Ap = Ause + (size_t)(row0 + srowA) * K + scol;
    const int lA0 = srowA * 32 + scol;
    const int lA1 = lA0 + 16 * 32;
    const int srowB = wv * 16 + (lane >> 2);
    const short* Bp = Bt + (size_t)(col0 + srowB) * K + scol;
    const int lB = srowB * 32 + scol;

    #define STAGE(buf, k0) do { \
        gld16(Ap + (k0),                &As[buf][lA0]); \
        gld16(Ap + (size_t)16*K + (k0), &As[buf][lA1]); \
        gld16(Bp + (k0),                &Bs[buf][lB]); \
    } while (0)

    STAGE(0, 0);
    __syncthreads();
    int cur = 0;
    for (int k0 = 0; k0 < K; k0 += 32) {
        if (k0 + 32 < K) STAGE(cur ^ 1, k0 + 32);
        bf16x8 af[4], bfr[2];
        #pragma unroll
        for (int i = 0; i < 4; ++i)
            af[i]  = *(const bf16x8*)&As[cur][(mbase + i * 16 + lr) * 32 + kg * 8];
        #pragma unroll
        for (int j = 0; j < 2; ++j)
            bfr[j] = *(const bf16x8*)&Bs[cur][(nbase + j * 16 + lr) * 32 + kg * 8];
        // operand swap: D = B^T-fragment x A-fragment -> C^T lane layout
        #pragma unroll
        for (int mi = 0; mi < 4; ++mi)
            #pragma unroll
            for (int ni = 0; ni < 2; ++ni)
                acc[mi][ni] = __builtin_amdgcn_mfma_f32_16x16x32_bf16(
                    bfr[ni], af[mi], acc[mi][ni], 0, 0, 0);
        __syncthreads();
        cur ^= 1;
    }
    #undef STAGE

    // epilogue: per lane, row = row0+mbase+mi*16+lr; cols = col0+nbase+ni*16+kg*4 .. +3
    float* Cf = (float*)Cout;
    short* Cb = (short*)Cout;
    short* Vb = (short*)Cout2;
    #pragma unroll
    for (int ni = 0; ni < 2; ++ni) {
        const int colb = col0 + nbase + ni * 16 + kg * 4;   // 4 consecutive cols
        float4 bz4;
        if (EPI == EPI_VALOA) {
            const float* bp = (colb < 256) ? (bias + colb)
                             : ((colb < 512) ? (bias2 + colb - 256) : (bias3 + colb - 512));
            bz4 = *(const float4*)bp;
        } else {
            bz4 = *(const float4*)(bias + colb);
        }
        #pragma unroll
        for (int mi = 0; mi < 4; ++mi) {
            int grow = row0 + mbase + mi * 16 + lr;
            if (grow >= M) continue;
            float v0 = acc[mi][ni][0] + bz4.x;
            float v1 = acc[mi][ni][1] + bz4.y;
            float v2 = acc[mi][ni][2] + bz4.z;
            float v3 = acc[mi][ni][3] + bz4.w;
            if (EPI == EPI_VALOA) {
                if (colb < 256) {
                    if (mask[grow]) { v0 = 0.f; v1 = 0.f; v2 = 0.f; v3 = 0.f; }
                    short4 s; s.x = f2bf(v0); s.y = f2bf(v1); s.z = f2bf(v2); s.w = f2bf(v3);
                    *(short4*)(Vb + (size_t)grow * 256 + colb) = s;
                } else {
                    short4 s; s.x = f2bf(v0); s.y = f2bf(v1); s.z = f2bf(v2); s.w = f2bf(v3);
                    *(short4*)(Cb + (size_t)grow * 384 + (colb - 256)) = s;
                }
                continue;
            }
            if (EPI == EPI_RES) {
                if (RESBF) {
                    short4 r = *(const short4*)(resb + (size_t)grow * N + colb);
                    v0 += bf2f(r.x); v1 += bf2f(r.y); v2 += bf2f(r.z); v3 += bf2f(r.w);
                } else {
                    float4 r = *(const float4*)(resf + (size_t)grow * N + colb);
                    v0 += r.x; v1 += r.y; v2 += r.z; v3 += r.w;
                }
            }
            if (EPI == EPI_RELU) {
                v0 = v0 > 0.f ? v0 : 0.f; v1 = v1 > 0.f ? v1 : 0.f;
                v2 = v2 > 0.f ? v2 : 0.f; v3 = v3 > 0.f ? v3 : 0.f;
            }
            if (OBF) {
                short4 s; s.x = f2bf(v0); s.y = f2bf(v1); s.z = f2bf(v2); s.w = f2bf(v3);
                *(short4*)(Cb + (size_t)grow * N + colb) = s;
            } else {
                float4 s; s.x = v0; s.y = v1; s.z = v2; s.w = v3;
                *(float4*)(Cf + (size_t)grow * N + colb) = s;
            }
        }
    }
}

// ---------------- MSDA with fused softmax; value + oa bf16 ----------------
// XCD-chunk swizzle of blockIdx -> bq (bijective): each XCD's L2 serves a contiguous
// spatial band (FETCH 86->30.5 MB measured). block = one bq (8 heads); phase-1 on
// threads 0..127; phase-2: 32-lane group per head, lane owns 2 dims.
__global__ __launch_bounds__(256) void msda_kernel(
    const short* __restrict__ value, const short* __restrict__ oa,
    const float* __restrict__ vr, short* __restrict__ out)
{
    __shared__ int pts[8 * 136];
    const int t = threadIdx.x;
    // bijective XCD-chunk swizzle: nwg = 2*Tc = 26588; q = 3323, r = 4
    const int nwgq = (2 * Tc) >> 3;          // 3323
    const int nwgr = (2 * Tc) & 7;           // 4
    const int xcd = blockIdx.x & 7;
    const int idx = blockIdx.x >> 3;
    const int bq = (xcd < nwgr ? xcd * (nwgq + 1)
                               : nwgr * (nwgq + 1) + (xcd - nwgr) * nwgq) + idx;
    const int b = (bq >= Tc) ? 1 : 0;
    const int qq = bq - b * Tc;

    if (t < 128) {
        const int g = t >> 4;        // group == head
        const int p = t & 15;
        const int lvl = p >> 2;
        const int St[4] = {0, 10000, 12500, 13125};
        int qi, Wq, qlvl;
        if (qq < 10000)      { qlvl = 0; qi = qq;         Wq = 100; }
        else if (qq < 12500) { qlvl = 1; qi = qq - 10000; Wq = 50; }
        else if (qq < 13125) { qlvl = 2; qi = qq - 12500; Wq = 25; }
        else                 { qlvl = 3; qi = qq - 13125; Wq = 13; }
        float base_x = (0.5f + (float)(qi % Wq)) / (vr[(b*4+qlvl)*2+0] * (float)Wq);
        float base_y = (0.5f + (float)(qi / Wq)) / (vr[(b*4+qlvl)*2+1] * (float)Wq);

        // softmax over 16 logits (one per lane; 16-lane group is wave-aligned)
        float logit = bf2f(oa[(size_t)bq * 384 + 256 + g * 16 + p]);
        float mx = logit;
        #pragma unroll
        for (int o = 8; o; o >>= 1) mx = fmaxf(mx, __shfl_xor(mx, o));
        float e = __expf(logit - mx);
        float sum = e;
        #pragma unroll
        for (int o = 8; o; o >>= 1) sum += __shfl_xor(sum, o);
        float aw = e * __frcp_rn(sum);

        const int w = (lvl == 0) ? 100 : ((lvl == 1) ? 50 : ((lvl == 2) ? 25 : 13));
        const int hh = w;
        const float wf = (float)w;
        const float refxw = base_x * vr[(b*4+lvl)*2+0] * wf;
        const float refyw = base_y * vr[(b*4+lvl)*2+1] * wf;
        const float ox = bf2f(oa[(size_t)bq * 384 + g * 32 + p * 2 + 0]);
        const float oy = bf2f(oa[(size_t)bq * 384 + g * 32 + p * 2 + 1]);
        float xf = refxw + ox - 0.5f;
        float yf = refyw + oy - 0.5f;
        float x0f = floorf(xf), y0f = floorf(yf);
        int x0 = (int)x0f, y0 = (int)y0f;
        float wx = xf - x0f, wy = yf - y0f;
        float w00 = (1.f - wx) * (1.f - wy) * aw;
        float w10 = wx * (1.f - wy) * aw;
        float w01 = (1.f - wx) * wy * aw;
        float w11 = wx * wy * aw;
        bool vx0 = (x0 >= 0) && (x0 < w);
        bool vx1 = (x0 + 1 >= 0) && (x0 + 1 < w);
        bool vy0 = (y0 >= 0) && (y0 < hh);
        bool vy1 = (y0 + 1 >= 0) && (y0 + 1 < hh);
        if (!(vx0 && vy0)) w00 = 0.f;
        if (!(vx1 && vy0)) w10 = 0.f;
        if (!(vx0 && vy1)) w01 = 0.f;
        if (!(vx1 && vy1)) w11 = 0.f;
        int cx0 = min(max(x0, 0), w - 1), cx1 = min(max(x0 + 1, 0), w - 1);
        int cy0 = min(max(y0, 0), hh - 1), cy1 = min(max(y0 + 1, 0), hh - 1);
        int rowbase = b * Tc + St[lvl];
        int slot = g * 136 + p * 8 + ((p >> 3) & 1) * 4;
        int4 wq4; wq4.x = __float_as_int(w00); wq4.y = __float_as_int(w10);
        wq4.z = __float_as_int(w01); wq4.w = __float_as_int(w11);
        int4 aq4;
        aq4.x = (rowbase + cy0 * w + cx0) * 512 + g * 64;
        aq4.y = (rowbase + cy0 * w + cx1) * 512 + g * 64;
        aq4.z = (rowbase + cy1 * w + cx0) * 512 + g * 64;
        aq4.w = (rowbase + cy1 * w + cx1) * 512 + g * 64;
        *(int4*)&pts[slot] = wq4;
        *(int4*)&pts[slot + 4] = aq4;
    }
    __syncthreads();

    const int group = t >> 5;               // head
    const int l32 = t & 31;
    const int d4 = (l32 & 15) * 4;
    const int ph = (l32 >> 4) * 8;
    const int xw = (l32 >> 4) * 4;
    const char* vbase = (const char*)value;
    float accL = 0.f, accH = 0.f;
    #pragma unroll
    for (int j = 0; j < 8; ++j) {
        int p = ph + j;
        int slot = group * 136 + p * 8 + xw;
        int4 wq = *(const int4*)&pts[slot];
        int4 aq = *(const int4*)&pts[slot + 4];
        unsigned u0 = *(const unsigned*)(vbase + (unsigned)(aq.x + d4));
        unsigned u1 = *(const unsigned*)(vbase + (unsigned)(aq.y + d4));
        unsigned u2 = *(const unsigned*)(vbase + (unsigned)(aq.z + d4));
        unsigned u3 = *(const unsigned*)(vbase + (unsigned)(aq.w + d4));
        float w00 = __int_as_float(wq.x), w10 = __int_as_float(wq.y);
        float w01 = __int_as_float(wq.z), w11 = __int_as_float(wq.w);
        // hi half: raw reinterpret (garbage low mantissa bits << bf16 rounding error)
        accL = fmaf(w00, bf_lo(u0), accL); accH = fmaf(w00, __int_as_float((int)u0), accH);
        accL = fmaf(w10, bf_lo(u1), accL); accH = fmaf(w10, __int_as_float((int)u1), accH);
        accL = fmaf(w01, bf_lo(u2), accL); accH = fmaf(w01, __int_as_float((int)u2), accH);
        accL = fmaf(w11, bf_lo(u3), accL); accH = fmaf(w11, __int_as_float((int)u3), accH);
    }
    accL += __shfl_xor(accL, 16);
    accH += __shfl_xor(accH, 16);
    if (l32 < 16) {
        unsigned pk = ((unsigned)(unsigned short)f2bf(accL)) |
                      (((unsigned)(unsigned short)f2bf(accH)) << 16);
        *(unsigned*)((char*)out + (size_t)bq * 512 + group * 64 + d4) = pk;
    }
}

extern "C" void kernel_launch(void* const* d_in, const int* in_sizes, int n_in,
                              void* d_out, int out_size, void* d_ws, size_t ws_size,
                              hipStream_t stream) {
    const float* src  = (const float*)d_in[0];
    const float* pos  = (const float*)d_in[1];
    const float* vr   = (const float*)d_in[2];
    const unsigned char* mask = (const unsigned char*)d_in[5];
    const float* Wv    = (const float*)d_in[6];
    const float* bv    = (const float*)d_in[7];
    const float* Woff  = (const float*)d_in[8];
    const float* boff  = (const float*)d_in[9];
    const float* Wattn = (const float*)d_in[10];
    const float* battn = (const float*)d_in[11];
    const float* Wout  = (const float*)d_in[12];
    const float* bout  = (const float*)d_in[13];
    const float* n1g   = (const float*)d_in[14];
    const float* n1b   = (const float*)d_in[15];
    const float* n2g   = (const float*)d_in[16];
    const float* n2b   = (const float*)d_in[17];
    const float* W1    = (const float*)d_in[18];
    const float* b1    = (const float*)d_in[19];
    const float* W2    = (const float*)d_in[20];
    const float* b2    = (const float*)d_in[21];
    float* out = (float*)d_out;

    const size_t R = (size_t)Bc * Tc;   // 26588

    // shorts/row: xb 256 | qb 256 | valb 256 | msdab 256 | oab 384 | srcb 256
    short* xb    = (short*)d_ws;
    short* qb    = xb + R * 256;
    short* valb  = qb + R * 256;
    short* msdab = valb + R * 256;
    short* oab   = msdab + R * 256;           // R*384
    short* srcb  = oab + R * 384;             // R*256 bf16 residual stream
    short* ln2b  = xb;                        // alias: xb dead by LN2 time
    short* hb    = qb;                        // alias: qb..oab >= R*1024, dead by ffn1
    short* wcT   = srcb + R * 256;            // 6*163840 ([640][256]: Wv|Woff|Wattn)
    short* woutT = wcT + 6 * 163840;          // 6*65536
    short* w1T   = woutT + 6 * 65536;         // 6*262144 ([1024][256])
    short* w2T   = w1T + 6 * 262144;          // 6*262144 ([256][1024])

    // one-time setup: all weight transposes in a single dispatch
    transpose_all<<<dim3(736, 1, 6), 256, 0, stream>>>(
        Wv, Woff, Wattn, Wout, W1, W2, wcT, woutT, w1T, w2T);

    const int M = (int)R;
    const int lnBlocks = (int)((R + 3) / 4);
    const int MT = (int)((R + 127) / 128);  // 208

    // layer 0 LN1 (fp32 src input)
    ln_kernel<<<lnBlocks, 256, 0, stream>>>(src, pos, n1g, n1b, xb, qb, M);

    for (int l = 0; l < NLAYERS; ++l) {
        // merged: [value | off | logits]; A = xb for cols<256, qb otherwise (1D swizzled grid)
        gemm_mfma<EPI_VALOA, 1, 0><<<MT * 10, 256, 0, stream>>>(
            xb, qb, wcT + (size_t)l * 163840, bv + l * Ec, boff + l * 256, battn + l * 128,
            nullptr, nullptr, mask, oab, valb, M, 640, 256);
        // MSDA (softmax fused) -> bf16
        msda_kernel<<<(int)R, 256, 0, stream>>>(valb, oab, vr, msdab);
        // src2 = cur + msda @ Wout + bout -> bf16 srcb
        if (l == 0)
            gemm_mfma<EPI_RES, 1, 0><<<MT * 4, 256, 0, stream>>>(
                msdab, nullptr, woutT + (size_t)l * 65536, bout + l * Ec, nullptr, nullptr,
                src, nullptr, nullptr, srcb, nullptr, M, 256, 256);
        else
            gemm_mfma<EPI_RES, 1, 1><<<MT * 4, 256, 0, stream>>>(
                msdab, nullptr, woutT + (size_t)l * 65536, bout + l * Ec, nullptr, nullptr,
                nullptr, srcb, nullptr, srcb, nullptr, M, 256, 256);
        // LN2 (bf16 in/out) -> ln2b
        ln_bf_kernel<<<lnBlocks, 256, 0, stream>>>(srcb, nullptr, n2g + l * Ec, n2b + l * Ec,
                                                   ln2b, nullptr, M);
        // h = relu(ln2 @ W1 + b1) -> bf16
        gemm_mfma<EPI_RELU, 1, 0><<<MT * 16, 256, 0, stream>>>(
            ln2b, nullptr, w1T + (size_t)l * 262144, b1 + l * FFNc, nullptr, nullptr,
            nullptr, nullptr, nullptr, hb, nullptr, M, 1024, 256);
        // src = src2 + h @ W2 + b2 ; last layer -> fp32 out, else bf16 srcb
        if (l < NLAYERS - 1) {
            gemm_mfma<EPI_RES, 1, 1><<<MT * 4, 256, 0, stream>>>(
                hb, nullptr, w2T + (size_t)l * 262144, b2 + l * Ec, nullptr, nullptr,
                nullptr, srcb, nullptr, srcb, nullptr, M, 256, 1024);
            // next-layer LN1 (+ q = x + pos, pos read fp32)
            ln_bf_kernel<<<lnBlocks, 256, 0, stream>>>(srcb, pos, n1g + (l + 1) * Ec,
                                                       n1b + (l + 1) * Ec, xb, qb, M);
        } else {
            gemm_mfma<EPI_RES, 0, 1><<<MT * 4, 256, 0, stream>>>(
                hb, nullptr, w2T + (size_t)l * 262144, b2 + l * Ec, nullptr, nullptr,
                nullptr, srcb, nullptr, out, nullptr, M, 256, 1024);
        }
    }
}